// Round 7
// baseline (279.141 us; speedup 1.0000x reference)
//
#include <hip/hip_runtime.h>
#include <math.h>

#define DEVI __device__ __forceinline__

using bf16x8 = __attribute__((ext_vector_type(8))) short;
using f32x4  = __attribute__((ext_vector_type(4))) float;

DEVI float b2f(unsigned short u) {
  union { unsigned int u; float f; } x; x.u = ((unsigned int)u) << 16; return x.f;
}
DEVI unsigned short f2b(float f) {
  union { float f; unsigned int u; } x; x.f = f;
  unsigned int r = (x.u + 0x7fffu + ((x.u >> 16) & 1u)) >> 16;
  return (unsigned short)r;
}
DEVI float gelu_f(float x) { return 0.5f * x * (1.0f + erff(x * 0.70710678118654752440f)); }

DEVI void wredxor2(float& a, float& b) {
  #pragma unroll
  for (int off = 32; off; off >>= 1) {
    a += __shfl_xor(a, off);
    b += __shfl_xor(b, off);
  }
}

template<int NW>
DEVI void breduce2(float& a, float& b) {
  __shared__ float buf[2 * NW];
  int lane = threadIdx.x & 63;
  int w = threadIdx.x >> 6;
  #pragma unroll
  for (int off = 32; off > 0; off >>= 1) {
    a += __shfl_down(a, off);
    b += __shfl_down(b, off);
  }
  if (lane == 0) { buf[w] = a; buf[NW + w] = b; }
  __syncthreads();
  float ra = 0.f, rb = 0.f;
  #pragma unroll
  for (int i = 0; i < NW; ++i) { ra += buf[i]; rb += buf[NW + i]; }
  a = ra; b = rb;
  __syncthreads();
}

DEVI void span_params(const int* st, const int* en, int span,
                      int& s, int& e, int& left, int& right) {
  int s0 = st[span], e0 = en[span];
  s = min(max(s0, 0), 511);
  e = max(s, min(e0, 511));
  left = max(0, s - 3);
  right = min(512, e + 4);
}

// bijective XCD chunk transform (m204)
DEVI int xcd_logical(int bid, int n) {
  int q = n >> 3, r = n & 7;
  int xcd = bid & 7, idx = bid >> 3;
  return (xcd < r ? xcd * (q + 1) : r * (q + 1) + (xcd - r) * q) + idx;
}

// ---------------- fused prep: weight cvt + seq LayerNorm + ctx gather ----------------
__global__ __launch_bounds__(256) void prep_kernel(
    const float* __restrict__ s0, const float* __restrict__ s1,
    const float* __restrict__ s2, const float* __restrict__ s3,
    const float* __restrict__ s4,
    unsigned short* __restrict__ d0, unsigned short* __restrict__ d1,
    unsigned short* __restrict__ d2, unsigned short* __restrict__ d3,
    unsigned short* __restrict__ d4,
    const float* __restrict__ seq, const float* __restrict__ ate_g,
    const float* __restrict__ ate_b, unsigned short* __restrict__ lnx,
    const int* __restrict__ st, const int* __restrict__ en,
    unsigned short* __restrict__ ctxA) {
  const int bid = blockIdx.x, tid = threadIdx.x;
  if (bid < 4032) {
    int i = bid * 256 + tid;
    const float* s; unsigned short* d; int j;
    if (i < 73728)       { s = s0; d = d0; j = i; }
    else if (i < 516096) { s = s1; d = d1; j = i - 73728; }
    else if (i < 663552) { s = s2; d = d2; j = i - 516096; }
    else if (i < 958464) { s = s3; d = d3; j = i - 663552; }
    else                 { s = s4; d = d4; j = i - 958464; }
    float4 v = reinterpret_cast<const float4*>(s)[j];
    ushort4 o;
    o.x = f2b(v.x); o.y = f2b(v.y); o.z = f2b(v.z); o.w = f2b(v.w);
    reinterpret_cast<ushort4*>(d)[j] = o;
  } else if (bid < 12224) {
    const int row = (bid - 4032) * 4 + (tid >> 6);
    const int lane = tid & 63;
    const float4* xr = reinterpret_cast<const float4*>(seq + (size_t)row * 768);
    float4 v[3];
    #pragma unroll
    for (int j = 0; j < 3; ++j) v[j] = xr[j * 64 + lane];
    float s = 0.f, q = 0.f;
    #pragma unroll
    for (int j = 0; j < 3; ++j) {
      s += v[j].x + v[j].y + v[j].z + v[j].w;
      q += v[j].x * v[j].x + v[j].y * v[j].y + v[j].z * v[j].z + v[j].w * v[j].w;
    }
    wredxor2(s, q);
    float mean = s * (1.0f / 768.0f);
    float rstd = rsqrtf(q * (1.0f / 768.0f) - mean * mean + 1e-5f);
    ushort4* orow = reinterpret_cast<ushort4*>(lnx + (size_t)row * 768);
    #pragma unroll
    for (int j = 0; j < 3; ++j) {
      float4 gv = reinterpret_cast<const float4*>(ate_g)[j * 64 + lane];
      float4 bv = reinterpret_cast<const float4*>(ate_b)[j * 64 + lane];
      ushort4 o;
      o.x = f2b((v[j].x - mean) * rstd * gv.x + bv.x);
      o.y = f2b((v[j].y - mean) * rstd * gv.y + bv.y);
      o.z = f2b((v[j].z - mean) * rstd * gv.z + bv.z);
      o.w = f2b((v[j].w - mean) * rstd * gv.w + bv.w);
      orow[j * 64 + lane] = o;
    }
  } else {
    if (tid >= 192) return;
    int r = bid - 12224;            // 0..3839 = span*15 + w
    int span = r / 15, w = r % 15;
    int s, e, left, right;
    span_params(st, en, span, s, e, left, right);
    int b = span >> 2;
    int tok = min(left + w, 511);
    const float4* src = reinterpret_cast<const float4*>(seq + ((size_t)b * 512 + tok) * 768);
    ushort4* dst = reinterpret_cast<ushort4*>(ctxA + (size_t)r * 768);
    float4 v = src[tid];
    ushort4 o;
    o.x = f2b(v.x); o.y = f2b(v.y); o.z = f2b(v.z); o.w = f2b(v.w);
    dst[tid] = o;
  }
}

// ---------------- MFMA bf16 GEMM body: BK=64, XOR-swizzled LDS, single buffer --------
// LDS layout: elem (row, c) stored at row*64 + (c ^ 8*(row&7)).
// Staged via pre-swizzled global source (global_load_lds writes linear lane*16B).
template<int BM, int BN, int WM, int WN>
DEVI void gemm_body64(const unsigned short* __restrict__ A,
                      const unsigned short* __restrict__ W,
                      const float* __restrict__ bias, unsigned short* __restrict__ C,
                      int M, int N, int K, bool act, int bm, int bn,
                      unsigned short* As, unsigned short* Bs) {
  constexpr int BK = 64;
  constexpr int CA = BM / 8;         // 1KB chunks (8 rows x 64 elems)
  constexpr int CB = BN / 8;
  constexpr int NWC = BN / WN;
  constexpr int FM = WM / 16, FN = WN / 16;
  const int tid = threadIdx.x;
  const int lane = tid & 63;
  const int wv = tid >> 6;
  const int wr = wv / NWC, wc = wv % NWC;
  const int l16 = lane & 15, lhi = lane >> 4;
  const int srow = lane >> 3;                      // row within 8-row chunk (=row&7)
  const int scol = 8 * ((lane & 7) ^ srow);        // pre-swizzled source col (elems)

  f32x4 acc[FM][FN] = {};
  const int nt = K / BK;

  for (int t = 0; t < nt; ++t) {
    const int k0 = t * BK;
    #pragma unroll
    for (int ch = wv; ch < CA; ch += 4)
      __builtin_amdgcn_global_load_lds(
          (const __attribute__((address_space(1))) void*)&A[(size_t)(bm + ch * 8 + srow) * K + k0 + scol],
          (__attribute__((address_space(3))) void*)&As[ch * 512], 16, 0, 0);
    #pragma unroll
    for (int ch = wv; ch < CB; ch += 4)
      __builtin_amdgcn_global_load_lds(
          (const __attribute__((address_space(1))) void*)&W[(size_t)(bn + ch * 8 + srow) * K + k0 + scol],
          (__attribute__((address_space(3))) void*)&Bs[ch * 512], 16, 0, 0);
    __syncthreads();
    #pragma unroll
    for (int kk = 0; kk < 2; ++kk) {
      bf16x8 af[FM], bfr[FN];
      #pragma unroll
      for (int fm = 0; fm < FM; ++fm) {
        int r = wr * WM + fm * 16 + l16;
        af[fm] = *reinterpret_cast<const bf16x8*>(&As[r * 64 + ((kk * 32 + lhi * 8) ^ ((r & 7) * 8))]);
      }
      #pragma unroll
      for (int fn = 0; fn < FN; ++fn) {
        int r = wc * WN + fn * 16 + l16;
        bfr[fn] = *reinterpret_cast<const bf16x8*>(&Bs[r * 64 + ((kk * 32 + lhi * 8) ^ ((r & 7) * 8))]);
      }
      #pragma unroll
      for (int fm = 0; fm < FM; ++fm)
        #pragma unroll
        for (int fn = 0; fn < FN; ++fn)
          acc[fm][fn] = __builtin_amdgcn_mfma_f32_16x16x32_bf16(af[fm], bfr[fn], acc[fm][fn], 0, 0, 0);
    }
    __syncthreads();
  }

  #pragma unroll
  for (int fm = 0; fm < FM; ++fm) {
    #pragma unroll
    for (int fn = 0; fn < FN; ++fn) {
      int col = bn + wc * WN + fn * 16 + l16;
      float bv = bias[col];
      #pragma unroll
      for (int i = 0; i < 4; ++i) {
        int row = bm + wr * WM + fm * 16 + lhi * 4 + i;
        float v = acc[fm][fn][i] + bv;
        if (act) v = gelu_f(v);
        C[(size_t)row * N + col] = f2b(v);
      }
    }
  }
}

// XCD-swizzled standalone GEMM (BK=64 swizzled body)
template<int BM, int BN, int WM, int WN, int ACT>
__global__ __launch_bounds__(256) void gemm_swz64(
    const unsigned short* __restrict__ A, const unsigned short* __restrict__ W,
    const float* __restrict__ bias, unsigned short* __restrict__ C,
    int M, int N, int K, int nbN) {
  __shared__ __align__(16) unsigned short As[BM * 64];
  __shared__ __align__(16) unsigned short Bs[BN * 64];
  int l = xcd_logical(blockIdx.x, gridDim.x);
  int mb = l / nbN, nb = l % nbN;
  gemm_body64<BM, BN, WM, WN>(A, W, bias, C, M, N, K, ACT != 0,
                              mb * BM, nb * BN, As, Bs);
}

// merged independent GEMMs: ATE hidden (768 blocks) + qkv (540 blocks), XCD-swizzled
__global__ __launch_bounds__(256) void dual_gemm_kernel(
    const unsigned short* __restrict__ lnx, const unsigned short* __restrict__ w1b,
    const float* __restrict__ b1, unsigned short* __restrict__ hate,
    const unsigned short* __restrict__ ctxA, const unsigned short* __restrict__ winb,
    const float* __restrict__ b_in, unsigned short* __restrict__ qkv) {
  __shared__ __align__(16) unsigned short As[128 * 64];
  __shared__ __align__(16) unsigned short Bs[128 * 64];
  if (blockIdx.x < 768) {
    int l = xcd_logical(blockIdx.x, 768);
    int mb = l / 3, nb = l % 3;
    gemm_body64<128, 128, 64, 64>(lnx, w1b, b1, hate, 32768, 384, 768, true,
                                  mb * 128, nb * 128, As, Bs);
  } else {
    int bid = blockIdx.x - 768;
    int l = xcd_logical(bid, 540);
    int mb = l / 18, nb = l % 18;
    gemm_body64<128, 128, 64, 64>(ctxA, winb, b_in, qkv, 3840, 2304, 768, false,
                                  mb * 128, nb * 128, As, Bs);
  }
}

// ---------------- merged: ATE head finish (bid<8192) + attention (else) ----------------
__global__ __launch_bounds__(256) void finattn_kernel(
    const unsigned short* __restrict__ h, const float* __restrict__ lng,
    const float* __restrict__ lnb, const float* __restrict__ w2,
    const float* __restrict__ b2, float* __restrict__ out,
    const unsigned short* __restrict__ qkv, const int* __restrict__ st,
    const int* __restrict__ en, unsigned short* __restrict__ ctxO) {
  __shared__ float qs[15][96], ks[15][96], vs[15][96];
  __shared__ float sc[15][16];
  const int tid = threadIdx.x;
  if (blockIdx.x < 8192) {
    const int row = blockIdx.x * 4 + (tid >> 6);
    const int lane = tid & 63;
    const unsigned short* hr = h + (size_t)row * 384 + lane * 6;
    ushort2 u0 = *reinterpret_cast<const ushort2*>(hr);
    ushort2 u1 = *reinterpret_cast<const ushort2*>(hr + 2);
    ushort2 u2 = *reinterpret_cast<const ushort2*>(hr + 4);
    float v[6] = { b2f(u0.x), b2f(u0.y), b2f(u1.x), b2f(u1.y), b2f(u2.x), b2f(u2.y) };
    float s = 0.f, q = 0.f;
    #pragma unroll
    for (int j = 0; j < 6; ++j) { s += v[j]; q += v[j] * v[j]; }
    wredxor2(s, q);
    float mean = s * (1.f / 384.f);
    float rstd = rsqrtf(q * (1.f / 384.f) - mean * mean + 1e-5f);
    const int c0 = lane * 6;
    float p0 = 0.f, p1 = 0.f;
    #pragma unroll
    for (int j = 0; j < 6; ++j) {
      float hl = (v[j] - mean) * rstd * lng[c0 + j] + lnb[c0 + j];
      p0 += hl * w2[c0 + j];
      p1 += hl * w2[384 + c0 + j];
    }
    wredxor2(p0, p1);
    if (lane == 0) {
      out[(size_t)row * 2]     = p0 + b2[0];
      out[(size_t)row * 2 + 1] = p1 + b2[1];
    }
    return;
  }
  const int blk = blockIdx.x - 8192;
  const int span = blk >> 3, hh = blk & 7;
  int s, e, left, right;
  span_params(st, en, span, s, e, left, right);
  const int nv = right - left;
  const int r0 = span * 15;
  const float scale = 0.10206207261596576f;   // 1/sqrt(96)
  if (tid < 180) {
    int w = tid / 12, dp = tid % 12, d = dp * 8;
    const unsigned short* rowp = qkv + (size_t)(r0 + w) * 2304 + hh * 96 + d;
    bf16x8 qv = *reinterpret_cast<const bf16x8*>(rowp);
    bf16x8 kv = *reinterpret_cast<const bf16x8*>(rowp + 768);
    bf16x8 vv = *reinterpret_cast<const bf16x8*>(rowp + 1536);
    #pragma unroll
    for (int j = 0; j < 8; ++j) {
      qs[w][d + j] = b2f((unsigned short)qv[j]) * scale;
      ks[w][d + j] = b2f((unsigned short)kv[j]);
      vs[w][d + j] = b2f((unsigned short)vv[j]);
    }
  }
  __syncthreads();
  if (tid < 225) {
    int i = tid / 15, j = tid % 15;
    float a = 0.f;
    #pragma unroll
    for (int d = 0; d < 96; ++d) a += qs[i][d] * ks[j][d];
    sc[i][j] = (j < nv) ? a : -3.402823466e38f;
  }
  __syncthreads();
  if (tid < 15) {
    int i = tid;
    float m = -3.402823466e38f;
    #pragma unroll
    for (int j = 0; j < 15; ++j) m = fmaxf(m, sc[i][j]);
    float ex[15];
    float ssum = 0.f;
    #pragma unroll
    for (int j = 0; j < 15; ++j) { ex[j] = expf(sc[i][j] - m); ssum += ex[j]; }
    float inv = 1.0f / ssum;
    #pragma unroll
    for (int j = 0; j < 15; ++j) sc[i][j] = ex[j] * inv;
  }
  __syncthreads();
  for (int idx = tid; idx < 720; idx += 256) {
    int w = idx / 48, dp = idx % 48, d = dp * 2;
    float o0 = 0.f, o1 = 0.f;
    #pragma unroll
    for (int j = 0; j < 15; ++j) {
      float p = sc[w][j];
      o0 += p * vs[j][d];
      o1 += p * vs[j][d + 1];
    }
    ushort2 o; o.x = f2b(o0); o.y = f2b(o1);
    *reinterpret_cast<ushort2*>(&ctxO[(size_t)(r0 + w) * 768 + hh * 96 + d]) = o;
  }
}

// ---------------- spanfuse: span means + fusion GEMV + gelu + span-mean ----------------
// grid 192 = (batch b)*3 + col-third h3. Writes fmean[b][c] fp32 for c in [h3*256, +256).
__global__ __launch_bounds__(256) void spanfuse_kernel(
    const float* __restrict__ seq, const unsigned short* __restrict__ projO,
    const int* __restrict__ st, const int* __restrict__ en,
    const unsigned short* __restrict__ fusb, const float* __restrict__ fus_b,
    float* __restrict__ fmean) {
  const int b = blockIdx.x / 3, h3 = blockIdx.x % 3;
  const int tid = threadIdx.x;
  __shared__ float comb[4][1536];
  #pragma unroll
  for (int n = 0; n < 4; ++n) {
    int span = b * 4 + n;
    int s, e, left, right;
    span_params(st, en, span, s, e, left, right);
    int e2 = min(e, s + 8);
    int cnt = e2 - s;
    int nv = right - left;
    float inva = (cnt > 0) ? 1.0f / (float)cnt : 0.f;
    float invc = 1.0f / (float)nv;
    for (int c = tid; c < 768; c += 256) {
      float sa = 0.f;
      for (int t = s; t < e2; ++t) sa += seq[((size_t)b * 512 + t) * 768 + c];
      comb[n][c] = (cnt > 0) ? sa * inva : seq[((size_t)b * 512) * 768 + c];
      float sc = 0.f;
      for (int w = 0; w < nv; ++w) sc += b2f(projO[(size_t)(span * 15 + w) * 768 + c]);
      comb[n][768 + c] = sc * invc;
    }
  }
  __syncthreads();
  const int c = h3 * 256 + tid;            // one output col per thread
  const bf16x8* wrow = reinterpret_cast<const bf16x8*>(fusb + (size_t)c * 1536);
  float d0 = 0.f, d1 = 0.f, d2 = 0.f, d3 = 0.f;
  for (int k8 = 0; k8 < 192; ++k8) {
    bf16x8 wv8 = wrow[k8];
    #pragma unroll
    for (int u = 0; u < 8; ++u) {
      float wf = b2f((unsigned short)wv8[u]);
      int k = k8 * 8 + u;
      d0 += comb[0][k] * wf;
      d1 += comb[1][k] * wf;
      d2 += comb[2][k] * wf;
      d3 += comb[3][k] * wf;
    }
  }
  float bias = fus_b[c];
  fmean[(size_t)b * 768 + c] = 0.25f * (gelu_f(d0 + bias) + gelu_f(d1 + bias) +
                                        gelu_f(d2 + bias) + gelu_f(d3 + bias));
}

// ---------------- APC finish: LN -> hidden GEMV -> LN -> head ----------------
__global__ __launch_bounds__(256) void apc_all_kernel(
    const float* __restrict__ fmean, const float* __restrict__ g,
    const float* __restrict__ bb, const unsigned short* __restrict__ senb,
    const float* __restrict__ b1, const float* __restrict__ lng,
    const float* __restrict__ lnb, const float* __restrict__ w2,
    const float* __restrict__ b2, float* __restrict__ out) {
  const int b = blockIdx.x, tid = threadIdx.x;
  __shared__ float xs[768];
  __shared__ float hs[384];
  float v[3];
  #pragma unroll
  for (int j = 0; j < 3; ++j) v[j] = fmean[(size_t)b * 768 + tid + j * 256];
  float s = v[0] + v[1] + v[2];
  float q = v[0] * v[0] + v[1] * v[1] + v[2] * v[2];
  breduce2<4>(s, q);
  float mean = s * (1.f / 768.f);
  float rstd = rsqrtf(q * (1.f / 768.f) - mean * mean + 1e-5f);
  #pragma unroll
  for (int j = 0; j < 3; ++j) {
    int c = tid + j * 256;
    xs[c] = (v[j] - mean) * rstd * g[c] + bb[c];
  }
  __syncthreads();
  for (int j = tid; j < 384; j += 256) {
    const bf16x8* wrp = reinterpret_cast<const bf16x8*>(senb + (size_t)j * 768);
    float dot = 0.f;
    #pragma unroll 4
    for (int k8 = 0; k8 < 96; ++k8) {
      bf16x8 wv = wrp[k8];
      #pragma unroll
      for (int u = 0; u < 8; ++u) dot += xs[k8 * 8 + u] * b2f((unsigned short)wv[u]);
    }
    hs[j] = gelu_f(dot + b1[j]);
  }
  __syncthreads();
  s = 0.f; q = 0.f;
  for (int j = tid; j < 384; j += 256) { float h = hs[j]; s += h; q += h * h; }
  breduce2<4>(s, q);
  mean = s * (1.f / 384.f);
  rstd = rsqrtf(q * (1.f / 384.f) - mean * mean + 1e-5f);
  float p0 = 0.f, p1 = 0.f;
  for (int j = tid; j < 384; j += 256) {
    float hl = (hs[j] - mean) * rstd * lng[j] + lnb[j];
    p0 += hl * w2[j];
    p1 += hl * w2[384 + j];
  }
  breduce2<4>(p0, p1);
  if (tid == 0) {
    out[b * 2]     = p0 + b2[0];
    out[b * 2 + 1] = p1 + b2[1];
  }
}

extern "C" void kernel_launch(void* const* d_in, const int* in_sizes, int n_in,
                              void* d_out, int out_size, void* d_ws, size_t ws_size,
                              hipStream_t stream) {
  const float* seq    = (const float*)d_in[0];
  const int*   st     = (const int*)d_in[1];
  const int*   en     = (const int*)d_in[2];
  const float* ate_g  = (const float*)d_in[3];
  const float* ate_b  = (const float*)d_in[4];
  const float* apc_g  = (const float*)d_in[5];
  const float* apc_b  = (const float*)d_in[6];
  const float* w_in   = (const float*)d_in[7];
  const float* b_in   = (const float*)d_in[8];
  const float* w_out  = (const float*)d_in[9];
  const float* b_out  = (const float*)d_in[10];
  const float* fus_w  = (const float*)d_in[11];
  const float* fus_b  = (const float*)d_in[12];
  const float* asp_w1 = (const float*)d_in[13];
  const float* asp_b1 = (const float*)d_in[14];
  const float* asp_lng= (const float*)d_in[15];
  const float* asp_lnb= (const float*)d_in[16];
  const float* asp_w2 = (const float*)d_in[17];
  const float* asp_b2 = (const float*)d_in[18];
  const float* sen_w1 = (const float*)d_in[19];
  const float* sen_b1 = (const float*)d_in[20];
  const float* sen_lng= (const float*)d_in[21];
  const float* sen_lnb= (const float*)d_in[22];
  const float* sen_w2 = (const float*)d_in[23];
  const float* sen_b2 = (const float*)d_in[24];
  float* out = (float*)d_out;

  char* wsb = (char*)d_ws;
  unsigned short* lnx   = (unsigned short*)(wsb + 0);          // 32768x768 bf16
  unsigned short* ctxA  = (unsigned short*)(wsb + 52428800);   // 3840x768
  unsigned short* qkvb  = (unsigned short*)(wsb + 58720256);   // 3840x2304
  unsigned short* ctxO  = (unsigned short*)(wsb + 77594624);   // 3840x768
  unsigned short* projO = (unsigned short*)(wsb + 83886080);   // 3840x768
  float*          fmean = (float*)(wsb + 89849856);            // 64x768 fp32
  const size_t off_w = 91275264;
  unsigned short* hate  = (unsigned short*)(wsb + off_w);             // 32768x384
  const size_t off_w2 = off_w + 25165824;
  unsigned short* w1b   = (unsigned short*)(wsb + off_w2);            // 384x768
  unsigned short* winb  = (unsigned short*)(wsb + off_w2 + 589824);   // 2304x768
  unsigned short* woutb = (unsigned short*)(wsb + off_w2 + 4128768);  // 768x768
  unsigned short* fusb  = (unsigned short*)(wsb + off_w2 + 5308416);  // 768x1536
  unsigned short* senb  = (unsigned short*)(wsb + off_w2 + 7667712);  // 384x768

  // 1) prep: cvt + ln_seq + gather
  prep_kernel<<<16064, 256, 0, stream>>>(asp_w1, w_in, w_out, fus_w, sen_w1,
                                         w1b, winb, woutb, fusb, senb,
                                         seq, ate_g, ate_b, lnx, st, en, ctxA);
  // 2) ATE hidden GEMM + qkv GEMM merged, XCD-swizzled, BK=64 swizzled LDS
  dual_gemm_kernel<<<1308, 256, 0, stream>>>(lnx, w1b, asp_b1, hate,
                                             ctxA, winb, b_in, qkvb);
  // 3) ATE head finish + attention merged
  finattn_kernel<<<10240, 256, 0, stream>>>(hate, asp_lng, asp_lnb, asp_w2, asp_b2, out,
                                            qkvb, st, en, ctxO);
  // 4) proj GEMM (BM=64: 60 mb x 6 nb = 360 blocks)
  gemm_swz64<64, 128, 32, 64, 0><<<360, 256, 0, stream>>>(
      ctxO, woutb, b_out, projO, 3840, 768, 768, 6);
  // 5) span means + fusion GEMV + gelu + span-mean
  spanfuse_kernel<<<192, 256, 0, stream>>>(seq, projO, st, en, fusb, fus_b, fmean);
  // 6) APC finish
  apc_all_kernel<<<64, 256, 0, stream>>>(fmean, apc_g, apc_b, senb, sen_b1,
                                         sen_lng, sen_lnb, sen_w2, sen_b2, out + 65536);
}

// Round 8
// 191.993 us; speedup vs baseline: 1.4539x; 1.4539x over previous
//
#include <hip/hip_runtime.h>
#include <math.h>

#define DEVI __device__ __forceinline__

using bf16x8 = __attribute__((ext_vector_type(8))) short;
using f32x4  = __attribute__((ext_vector_type(4))) float;

DEVI float b2f(unsigned short u) {
  union { unsigned int u; float f; } x; x.u = ((unsigned int)u) << 16; return x.f;
}
DEVI unsigned short f2b(float f) {
  union { float f; unsigned int u; } x; x.f = f;
  unsigned int r = (x.u + 0x7fffu + ((x.u >> 16) & 1u)) >> 16;
  return (unsigned short)r;
}
DEVI float gelu_f(float x) { return 0.5f * x * (1.0f + erff(x * 0.70710678118654752440f)); }

DEVI void wredxor2(float& a, float& b) {
  #pragma unroll
  for (int off = 32; off; off >>= 1) {
    a += __shfl_xor(a, off);
    b += __shfl_xor(b, off);
  }
}

template<int NW>
DEVI void breduce2(float& a, float& b) {
  __shared__ float buf[2 * NW];
  int lane = threadIdx.x & 63;
  int w = threadIdx.x >> 6;
  #pragma unroll
  for (int off = 32; off > 0; off >>= 1) {
    a += __shfl_down(a, off);
    b += __shfl_down(b, off);
  }
  if (lane == 0) { buf[w] = a; buf[NW + w] = b; }
  __syncthreads();
  float ra = 0.f, rb = 0.f;
  #pragma unroll
  for (int i = 0; i < NW; ++i) { ra += buf[i]; rb += buf[NW + i]; }
  a = ra; b = rb;
  __syncthreads();
}

DEVI void span_params(const int* st, const int* en, int span,
                      int& s, int& e, int& left, int& right) {
  int s0 = st[span], e0 = en[span];
  s = min(max(s0, 0), 511);
  e = max(s, min(e0, 511));
  left = max(0, s - 3);
  right = min(512, e + 4);
}

// bijective XCD chunk transform (m204)
DEVI int xcd_logical(int bid, int n) {
  int q = n >> 3, r = n & 7;
  int xcd = bid & 7, idx = bid >> 3;
  return (xcd < r ? xcd * (q + 1) : r * (q + 1) + (xcd - r) * q) + idx;
}

// ---------------- fused prep: weight cvt + seq LayerNorm + ctx gather ----------------
__global__ __launch_bounds__(256) void prep_kernel(
    const float* __restrict__ s0, const float* __restrict__ s1,
    const float* __restrict__ s2, const float* __restrict__ s3,
    const float* __restrict__ s4,
    unsigned short* __restrict__ d0, unsigned short* __restrict__ d1,
    unsigned short* __restrict__ d2, unsigned short* __restrict__ d3,
    unsigned short* __restrict__ d4,
    const float* __restrict__ seq, const float* __restrict__ ate_g,
    const float* __restrict__ ate_b, unsigned short* __restrict__ lnx,
    const int* __restrict__ st, const int* __restrict__ en,
    unsigned short* __restrict__ ctxA) {
  const int bid = blockIdx.x, tid = threadIdx.x;
  if (bid < 4032) {
    int i = bid * 256 + tid;
    const float* s; unsigned short* d; int j;
    if (i < 73728)       { s = s0; d = d0; j = i; }
    else if (i < 516096) { s = s1; d = d1; j = i - 73728; }
    else if (i < 663552) { s = s2; d = d2; j = i - 516096; }
    else if (i < 958464) { s = s3; d = d3; j = i - 663552; }
    else                 { s = s4; d = d4; j = i - 958464; }
    float4 v = reinterpret_cast<const float4*>(s)[j];
    ushort4 o;
    o.x = f2b(v.x); o.y = f2b(v.y); o.z = f2b(v.z); o.w = f2b(v.w);
    reinterpret_cast<ushort4*>(d)[j] = o;
  } else if (bid < 12224) {
    const int row = (bid - 4032) * 4 + (tid >> 6);
    const int lane = tid & 63;
    const float4* xr = reinterpret_cast<const float4*>(seq + (size_t)row * 768);
    float4 v[3];
    #pragma unroll
    for (int j = 0; j < 3; ++j) v[j] = xr[j * 64 + lane];
    float s = 0.f, q = 0.f;
    #pragma unroll
    for (int j = 0; j < 3; ++j) {
      s += v[j].x + v[j].y + v[j].z + v[j].w;
      q += v[j].x * v[j].x + v[j].y * v[j].y + v[j].z * v[j].z + v[j].w * v[j].w;
    }
    wredxor2(s, q);
    float mean = s * (1.0f / 768.0f);
    float rstd = rsqrtf(q * (1.0f / 768.0f) - mean * mean + 1e-5f);
    ushort4* orow = reinterpret_cast<ushort4*>(lnx + (size_t)row * 768);
    #pragma unroll
    for (int j = 0; j < 3; ++j) {
      float4 gv = reinterpret_cast<const float4*>(ate_g)[j * 64 + lane];
      float4 bv = reinterpret_cast<const float4*>(ate_b)[j * 64 + lane];
      ushort4 o;
      o.x = f2b((v[j].x - mean) * rstd * gv.x + bv.x);
      o.y = f2b((v[j].y - mean) * rstd * gv.y + bv.y);
      o.z = f2b((v[j].z - mean) * rstd * gv.z + bv.z);
      o.w = f2b((v[j].w - mean) * rstd * gv.w + bv.w);
      orow[j * 64 + lane] = o;
    }
  } else {
    if (tid >= 192) return;
    int r = bid - 12224;            // 0..3839 = span*15 + w
    int span = r / 15, w = r % 15;
    int s, e, left, right;
    span_params(st, en, span, s, e, left, right);
    int b = span >> 2;
    int tok = min(left + w, 511);
    const float4* src = reinterpret_cast<const float4*>(seq + ((size_t)b * 512 + tok) * 768);
    ushort4* dst = reinterpret_cast<ushort4*>(ctxA + (size_t)r * 768);
    float4 v = src[tid];
    ushort4 o;
    o.x = f2b(v.x); o.y = f2b(v.y); o.z = f2b(v.z); o.w = f2b(v.w);
    dst[tid] = o;
  }
}

// ---------------- MFMA bf16 GEMM body: BK=64, XOR-swizzled LDS, single buffer --------
// LDS layout: elem (row, c) stored at row*64 + (c ^ 8*(row&7)).
template<int BM, int BN, int WM, int WN>
DEVI void gemm_body64(const unsigned short* __restrict__ A,
                      const unsigned short* __restrict__ W,
                      const float* __restrict__ bias, unsigned short* __restrict__ C,
                      int M, int N, int K, bool act, int bm, int bn,
                      unsigned short* As, unsigned short* Bs) {
  constexpr int BK = 64;
  constexpr int CA = BM / 8;
  constexpr int CB = BN / 8;
  constexpr int NWC = BN / WN;
  constexpr int FM = WM / 16, FN = WN / 16;
  const int tid = threadIdx.x;
  const int lane = tid & 63;
  const int wv = tid >> 6;
  const int wr = wv / NWC, wc = wv % NWC;
  const int l16 = lane & 15, lhi = lane >> 4;
  const int srow = lane >> 3;
  const int scol = 8 * ((lane & 7) ^ srow);

  f32x4 acc[FM][FN] = {};
  const int nt = K / BK;

  for (int t = 0; t < nt; ++t) {
    const int k0 = t * BK;
    #pragma unroll
    for (int ch = wv; ch < CA; ch += 4)
      __builtin_amdgcn_global_load_lds(
          (const __attribute__((address_space(1))) void*)&A[(size_t)(bm + ch * 8 + srow) * K + k0 + scol],
          (__attribute__((address_space(3))) void*)&As[ch * 512], 16, 0, 0);
    #pragma unroll
    for (int ch = wv; ch < CB; ch += 4)
      __builtin_amdgcn_global_load_lds(
          (const __attribute__((address_space(1))) void*)&W[(size_t)(bn + ch * 8 + srow) * K + k0 + scol],
          (__attribute__((address_space(3))) void*)&Bs[ch * 512], 16, 0, 0);
    __syncthreads();
    #pragma unroll
    for (int kk = 0; kk < 2; ++kk) {
      bf16x8 af[FM], bfr[FN];
      #pragma unroll
      for (int fm = 0; fm < FM; ++fm) {
        int r = wr * WM + fm * 16 + l16;
        af[fm] = *reinterpret_cast<const bf16x8*>(&As[r * 64 + ((kk * 32 + lhi * 8) ^ ((r & 7) * 8))]);
      }
      #pragma unroll
      for (int fn = 0; fn < FN; ++fn) {
        int r = wc * WN + fn * 16 + l16;
        bfr[fn] = *reinterpret_cast<const bf16x8*>(&Bs[r * 64 + ((kk * 32 + lhi * 8) ^ ((r & 7) * 8))]);
      }
      #pragma unroll
      for (int fm = 0; fm < FM; ++fm)
        #pragma unroll
        for (int fn = 0; fn < FN; ++fn)
          acc[fm][fn] = __builtin_amdgcn_mfma_f32_16x16x32_bf16(af[fm], bfr[fn], acc[fm][fn], 0, 0, 0);
    }
    __syncthreads();
  }

  #pragma unroll
  for (int fm = 0; fm < FM; ++fm) {
    #pragma unroll
    for (int fn = 0; fn < FN; ++fn) {
      int col = bn + wc * WN + fn * 16 + l16;
      float bv = bias[col];
      #pragma unroll
      for (int i = 0; i < 4; ++i) {
        int row = bm + wr * WM + fm * 16 + lhi * 4 + i;
        float v = acc[fm][fn][i] + bv;
        if (act) v = gelu_f(v);
        C[(size_t)row * N + col] = f2b(v);
      }
    }
  }
}

// XCD-swizzled standalone GEMM (BK=64 swizzled body)
template<int BM, int BN, int WM, int WN, int ACT>
__global__ __launch_bounds__(256) void gemm_swz64(
    const unsigned short* __restrict__ A, const unsigned short* __restrict__ W,
    const float* __restrict__ bias, unsigned short* __restrict__ C,
    int M, int N, int K, int nbN) {
  __shared__ __align__(16) unsigned short As[BM * 64];
  __shared__ __align__(16) unsigned short Bs[BN * 64];
  int l = xcd_logical(blockIdx.x, gridDim.x);
  int mb = l / nbN, nb = l % nbN;
  gemm_body64<BM, BN, WM, WN>(A, W, bias, C, M, N, K, ACT != 0,
                              mb * BM, nb * BN, As, Bs);
}

// merged independent GEMMs: ATE hidden (768 blocks) + qkv (540 blocks), XCD-swizzled
__global__ __launch_bounds__(256) void dual_gemm_kernel(
    const unsigned short* __restrict__ lnx, const unsigned short* __restrict__ w1b,
    const float* __restrict__ b1, unsigned short* __restrict__ hate,
    const unsigned short* __restrict__ ctxA, const unsigned short* __restrict__ winb,
    const float* __restrict__ b_in, unsigned short* __restrict__ qkv) {
  __shared__ __align__(16) unsigned short As[128 * 64];
  __shared__ __align__(16) unsigned short Bs[128 * 64];
  if (blockIdx.x < 768) {
    int l = xcd_logical(blockIdx.x, 768);
    int mb = l / 3, nb = l % 3;
    gemm_body64<128, 128, 64, 64>(lnx, w1b, b1, hate, 32768, 384, 768, true,
                                  mb * 128, nb * 128, As, Bs);
  } else {
    int bid = blockIdx.x - 768;
    int l = xcd_logical(bid, 540);
    int mb = l / 18, nb = l % 18;
    gemm_body64<128, 128, 64, 64>(ctxA, winb, b_in, qkv, 3840, 2304, 768, false,
                                  mb * 128, nb * 128, As, Bs);
  }
}

// ---------------- merged: ATE head finish (bid<8192) + attention (else) ----------------
__global__ __launch_bounds__(256) void finattn_kernel(
    const unsigned short* __restrict__ h, const float* __restrict__ lng,
    const float* __restrict__ lnb, const float* __restrict__ w2,
    const float* __restrict__ b2, float* __restrict__ out,
    const unsigned short* __restrict__ qkv, const int* __restrict__ st,
    const int* __restrict__ en, unsigned short* __restrict__ ctxO) {
  __shared__ float qs[15][96], ks[15][96], vs[15][96];
  __shared__ float sc[15][16];
  const int tid = threadIdx.x;
  if (blockIdx.x < 8192) {
    const int row = blockIdx.x * 4 + (tid >> 6);
    const int lane = tid & 63;
    const unsigned short* hr = h + (size_t)row * 384 + lane * 6;
    ushort2 u0 = *reinterpret_cast<const ushort2*>(hr);
    ushort2 u1 = *reinterpret_cast<const ushort2*>(hr + 2);
    ushort2 u2 = *reinterpret_cast<const ushort2*>(hr + 4);
    float v[6] = { b2f(u0.x), b2f(u0.y), b2f(u1.x), b2f(u1.y), b2f(u2.x), b2f(u2.y) };
    float s = 0.f, q = 0.f;
    #pragma unroll
    for (int j = 0; j < 6; ++j) { s += v[j]; q += v[j] * v[j]; }
    wredxor2(s, q);
    float mean = s * (1.f / 384.f);
    float rstd = rsqrtf(q * (1.f / 384.f) - mean * mean + 1e-5f);
    const int c0 = lane * 6;
    float p0 = 0.f, p1 = 0.f;
    #pragma unroll
    for (int j = 0; j < 6; ++j) {
      float hl = (v[j] - mean) * rstd * lng[c0 + j] + lnb[c0 + j];
      p0 += hl * w2[c0 + j];
      p1 += hl * w2[384 + c0 + j];
    }
    wredxor2(p0, p1);
    if (lane == 0) {
      out[(size_t)row * 2]     = p0 + b2[0];
      out[(size_t)row * 2 + 1] = p1 + b2[1];
    }
    return;
  }
  const int blk = blockIdx.x - 8192;
  const int span = blk >> 3, hh = blk & 7;
  int s, e, left, right;
  span_params(st, en, span, s, e, left, right);
  const int nv = right - left;
  const int r0 = span * 15;
  const float scale = 0.10206207261596576f;   // 1/sqrt(96)
  if (tid < 180) {
    int w = tid / 12, dp = tid % 12, d = dp * 8;
    const unsigned short* rowp = qkv + (size_t)(r0 + w) * 2304 + hh * 96 + d;
    bf16x8 qv = *reinterpret_cast<const bf16x8*>(rowp);
    bf16x8 kv = *reinterpret_cast<const bf16x8*>(rowp + 768);
    bf16x8 vv = *reinterpret_cast<const bf16x8*>(rowp + 1536);
    #pragma unroll
    for (int j = 0; j < 8; ++j) {
      qs[w][d + j] = b2f((unsigned short)qv[j]) * scale;
      ks[w][d + j] = b2f((unsigned short)kv[j]);
      vs[w][d + j] = b2f((unsigned short)vv[j]);
    }
  }
  __syncthreads();
  if (tid < 225) {
    int i = tid / 15, j = tid % 15;
    float a = 0.f;
    #pragma unroll
    for (int d = 0; d < 96; ++d) a += qs[i][d] * ks[j][d];
    sc[i][j] = (j < nv) ? a : -3.402823466e38f;
  }
  __syncthreads();
  if (tid < 15) {
    int i = tid;
    float m = -3.402823466e38f;
    #pragma unroll
    for (int j = 0; j < 15; ++j) m = fmaxf(m, sc[i][j]);
    float ex[15];
    float ssum = 0.f;
    #pragma unroll
    for (int j = 0; j < 15; ++j) { ex[j] = expf(sc[i][j] - m); ssum += ex[j]; }
    float inv = 1.0f / ssum;
    #pragma unroll
    for (int j = 0; j < 15; ++j) sc[i][j] = ex[j] * inv;
  }
  __syncthreads();
  for (int idx = tid; idx < 720; idx += 256) {
    int w = idx / 48, dp = idx % 48, d = dp * 2;
    float o0 = 0.f, o1 = 0.f;
    #pragma unroll
    for (int j = 0; j < 15; ++j) {
      float p = sc[w][j];
      o0 += p * vs[j][d];
      o1 += p * vs[j][d + 1];
    }
    ushort2 o; o.x = f2b(o0); o.y = f2b(o1);
    *reinterpret_cast<ushort2*>(&ctxO[(size_t)(r0 + w) * 768 + hh * 96 + d]) = o;
  }
}

// ---------------- masked means -> combined[span][0:768]=asp, [768:1536]=ctx ----------------
__global__ __launch_bounds__(256) void means_kernel(
    const float* __restrict__ seq, const unsigned short* __restrict__ projO,
    const int* __restrict__ st, const int* __restrict__ en,
    unsigned short* __restrict__ comb) {
  const int span = blockIdx.x;
  int s, e, left, right;
  span_params(st, en, span, s, e, left, right);
  int b = span >> 2;
  int e2 = min(e, s + 8);
  int cnt = e2 - s;
  int nv = right - left;
  float inva = (cnt > 0) ? 1.0f / (float)cnt : 0.f;
  float invc = 1.0f / (float)nv;
  for (int c = threadIdx.x; c < 768; c += 256) {
    float sa = 0.f;
    for (int t = s; t < e2; ++t) sa += seq[((size_t)b * 512 + t) * 768 + c];
    float asp = (cnt > 0) ? sa * inva : seq[((size_t)b * 512) * 768 + c];
    comb[(size_t)span * 1536 + c] = f2b(asp);
    float sc_ = 0.f;
    for (int w = 0; w < nv; ++w) sc_ += b2f(projO[(size_t)(span * 15 + w) * 768 + c]);
    comb[(size_t)span * 1536 + 768 + c] = f2b(sc_ * invc);
  }
}

// ---------------- APC all-in-one: span-mean -> LN -> hidden GEMV -> LN -> head ---------
__global__ __launch_bounds__(256) void apc_all_kernel(
    const unsigned short* __restrict__ fused, const float* __restrict__ g,
    const float* __restrict__ bb, const unsigned short* __restrict__ senb,
    const float* __restrict__ b1, const float* __restrict__ lng,
    const float* __restrict__ lnb, const float* __restrict__ w2,
    const float* __restrict__ b2, float* __restrict__ out) {
  const int b = blockIdx.x, tid = threadIdx.x;
  __shared__ float xs[768];
  __shared__ float hs[384];
  float v[3];
  #pragma unroll
  for (int j = 0; j < 3; ++j) {
    int c = tid + j * 256;
    float a = 0.f;
    #pragma unroll
    for (int n = 0; n < 4; ++n) a += b2f(fused[((size_t)(b * 4 + n)) * 768 + c]);
    v[j] = 0.25f * a;
  }
  float s = v[0] + v[1] + v[2];
  float q = v[0] * v[0] + v[1] * v[1] + v[2] * v[2];
  breduce2<4>(s, q);
  float mean = s * (1.f / 768.f);
  float rstd = rsqrtf(q * (1.f / 768.f) - mean * mean + 1e-5f);
  #pragma unroll
  for (int j = 0; j < 3; ++j) {
    int c = tid + j * 256;
    xs[c] = (v[j] - mean) * rstd * g[c] + bb[c];
  }
  __syncthreads();
  for (int j = tid; j < 384; j += 256) {
    const bf16x8* wrp = reinterpret_cast<const bf16x8*>(senb + (size_t)j * 768);
    float dot = 0.f;
    #pragma unroll 4
    for (int k8 = 0; k8 < 96; ++k8) {
      bf16x8 wv = wrp[k8];
      #pragma unroll
      for (int u = 0; u < 8; ++u) dot += xs[k8 * 8 + u] * b2f((unsigned short)wv[u]);
    }
    hs[j] = gelu_f(dot + b1[j]);
  }
  __syncthreads();
  s = 0.f; q = 0.f;
  for (int j = tid; j < 384; j += 256) { float h = hs[j]; s += h; q += h * h; }
  breduce2<4>(s, q);
  mean = s * (1.f / 384.f);
  rstd = rsqrtf(q * (1.f / 384.f) - mean * mean + 1e-5f);
  float p0 = 0.f, p1 = 0.f;
  for (int j = tid; j < 384; j += 256) {
    float hl = (hs[j] - mean) * rstd * lng[j] + lnb[j];
    p0 += hl * w2[j];
    p1 += hl * w2[384 + j];
  }
  breduce2<4>(p0, p1);
  if (tid == 0) {
    out[b * 2]     = p0 + b2[0];
    out[b * 2 + 1] = p1 + b2[1];
  }
}

extern "C" void kernel_launch(void* const* d_in, const int* in_sizes, int n_in,
                              void* d_out, int out_size, void* d_ws, size_t ws_size,
                              hipStream_t stream) {
  const float* seq    = (const float*)d_in[0];
  const int*   st     = (const int*)d_in[1];
  const int*   en     = (const int*)d_in[2];
  const float* ate_g  = (const float*)d_in[3];
  const float* ate_b  = (const float*)d_in[4];
  const float* apc_g  = (const float*)d_in[5];
  const float* apc_b  = (const float*)d_in[6];
  const float* w_in   = (const float*)d_in[7];
  const float* b_in   = (const float*)d_in[8];
  const float* w_out  = (const float*)d_in[9];
  const float* b_out  = (const float*)d_in[10];
  const float* fus_w  = (const float*)d_in[11];
  const float* fus_b  = (const float*)d_in[12];
  const float* asp_w1 = (const float*)d_in[13];
  const float* asp_b1 = (const float*)d_in[14];
  const float* asp_lng= (const float*)d_in[15];
  const float* asp_lnb= (const float*)d_in[16];
  const float* asp_w2 = (const float*)d_in[17];
  const float* asp_b2 = (const float*)d_in[18];
  const float* sen_w1 = (const float*)d_in[19];
  const float* sen_b1 = (const float*)d_in[20];
  const float* sen_lng= (const float*)d_in[21];
  const float* sen_lnb= (const float*)d_in[22];
  const float* sen_w2 = (const float*)d_in[23];
  const float* sen_b2 = (const float*)d_in[24];
  float* out = (float*)d_out;

  char* wsb = (char*)d_ws;
  unsigned short* lnx   = (unsigned short*)(wsb + 0);          // 32768x768 bf16
  unsigned short* ctxA  = (unsigned short*)(wsb + 52428800);   // 3840x768
  unsigned short* qkvb  = (unsigned short*)(wsb + 58720256);   // 3840x2304
  unsigned short* ctxO  = (unsigned short*)(wsb + 77594624);   // 3840x768
  unsigned short* projO = (unsigned short*)(wsb + 83886080);   // 3840x768
  unsigned short* comb  = (unsigned short*)(wsb + 89849856);   // 256x1536
  unsigned short* fusO  = (unsigned short*)(wsb + 90636288);   // 256x768
  const size_t off_w = 91275264;
  unsigned short* hate  = (unsigned short*)(wsb + off_w);             // 32768x384
  const size_t off_w2 = off_w + 25165824;
  unsigned short* w1b   = (unsigned short*)(wsb + off_w2);            // 384x768
  unsigned short* winb  = (unsigned short*)(wsb + off_w2 + 589824);   // 2304x768
  unsigned short* woutb = (unsigned short*)(wsb + off_w2 + 4128768);  // 768x768
  unsigned short* fusb  = (unsigned short*)(wsb + off_w2 + 5308416);  // 768x1536
  unsigned short* senb  = (unsigned short*)(wsb + off_w2 + 7667712);  // 384x768

  // 1) prep: cvt + ln_seq + gather
  prep_kernel<<<16064, 256, 0, stream>>>(asp_w1, w_in, w_out, fus_w, sen_w1,
                                         w1b, winb, woutb, fusb, senb,
                                         seq, ate_g, ate_b, lnx, st, en, ctxA);
  // 2) ATE hidden GEMM + qkv GEMM merged, XCD-swizzled, BK=64 swizzled LDS
  dual_gemm_kernel<<<1308, 256, 0, stream>>>(lnx, w1b, asp_b1, hate,
                                             ctxA, winb, b_in, qkvb);
  // 3) ATE head finish + attention merged
  finattn_kernel<<<10240, 256, 0, stream>>>(hate, asp_lng, asp_lnb, asp_w2, asp_b2, out,
                                            qkvb, st, en, ctxO);
  // 4) proj GEMM (BM=64: 60 mb x 6 nb = 360 blocks)
  gemm_swz64<64, 128, 32, 64, 0><<<360, 256, 0, stream>>>(
      ctxO, woutb, b_out, projO, 3840, 768, 768, 6);
  // 5) masked means
  means_kernel<<<256, 256, 0, stream>>>(seq, projO, st, en, comb);
  // 6) fusion GEMM (BM=BN=64: 4 mb x 12 nb = 48 blocks)
  gemm_swz64<64, 64, 32, 32, 1><<<48, 256, 0, stream>>>(
      comb, fusb, fus_b, fusO, 256, 768, 1536, 12);
  // 7) APC all-in-one
  apc_all_kernel<<<64, 256, 0, stream>>>(fusO, apc_g, apc_b, senb, sen_b1,
                                         sen_lng, sen_lnb, sen_w2, sen_b2, out + 65536);
}

// Round 9
// 188.021 us; speedup vs baseline: 1.4846x; 1.0211x over previous
//
#include <hip/hip_runtime.h>
#include <math.h>

#define DEVI __device__ __forceinline__

using bf16x8 = __attribute__((ext_vector_type(8))) short;
using f32x4  = __attribute__((ext_vector_type(4))) float;

DEVI float b2f(unsigned short u) {
  union { unsigned int u; float f; } x; x.u = ((unsigned int)u) << 16; return x.f;
}
DEVI unsigned short f2b(float f) {
  union { float f; unsigned int u; } x; x.f = f;
  unsigned int r = (x.u + 0x7fffu + ((x.u >> 16) & 1u)) >> 16;
  return (unsigned short)r;
}
DEVI float gelu_f(float x) { return 0.5f * x * (1.0f + erff(x * 0.70710678118654752440f)); }

DEVI void wredxor2(float& a, float& b) {
  #pragma unroll
  for (int off = 32; off; off >>= 1) {
    a += __shfl_xor(a, off);
    b += __shfl_xor(b, off);
  }
}

template<int NW>
DEVI void breduce2(float& a, float& b) {
  __shared__ float buf[2 * NW];
  int lane = threadIdx.x & 63;
  int w = threadIdx.x >> 6;
  #pragma unroll
  for (int off = 32; off > 0; off >>= 1) {
    a += __shfl_down(a, off);
    b += __shfl_down(b, off);
  }
  if (lane == 0) { buf[w] = a; buf[NW + w] = b; }
  __syncthreads();
  float ra = 0.f, rb = 0.f;
  #pragma unroll
  for (int i = 0; i < NW; ++i) { ra += buf[i]; rb += buf[NW + i]; }
  a = ra; b = rb;
  __syncthreads();
}

DEVI void span_params(const int* st, const int* en, int span,
                      int& s, int& e, int& left, int& right) {
  int s0 = st[span], e0 = en[span];
  s = min(max(s0, 0), 511);
  e = max(s, min(e0, 511));
  left = max(0, s - 3);
  right = min(512, e + 4);
}

// bijective XCD chunk transform (m204)
DEVI int xcd_logical(int bid, int n) {
  int q = n >> 3, r = n & 7;
  int xcd = bid & 7, idx = bid >> 3;
  return (xcd < r ? xcd * (q + 1) : r * (q + 1) + (xcd - r) * q) + idx;
}

// ---------------- fused prep: weight cvt + seq LayerNorm + ctx gather ----------------
__global__ __launch_bounds__(256) void prep_kernel(
    const float* __restrict__ s0, const float* __restrict__ s1,
    const float* __restrict__ s2, const float* __restrict__ s3,
    const float* __restrict__ s4,
    unsigned short* __restrict__ d0, unsigned short* __restrict__ d1,
    unsigned short* __restrict__ d2, unsigned short* __restrict__ d3,
    unsigned short* __restrict__ d4,
    const float* __restrict__ seq, const float* __restrict__ ate_g,
    const float* __restrict__ ate_b, unsigned short* __restrict__ lnx,
    const int* __restrict__ st, const int* __restrict__ en,
    unsigned short* __restrict__ ctxA) {
  const int bid = blockIdx.x, tid = threadIdx.x;
  if (bid < 4032) {
    int i = bid * 256 + tid;
    const float* s; unsigned short* d; int j;
    if (i < 73728)       { s = s0; d = d0; j = i; }
    else if (i < 516096) { s = s1; d = d1; j = i - 73728; }
    else if (i < 663552) { s = s2; d = d2; j = i - 516096; }
    else if (i < 958464) { s = s3; d = d3; j = i - 663552; }
    else                 { s = s4; d = d4; j = i - 958464; }
    float4 v = reinterpret_cast<const float4*>(s)[j];
    ushort4 o;
    o.x = f2b(v.x); o.y = f2b(v.y); o.z = f2b(v.z); o.w = f2b(v.w);
    reinterpret_cast<ushort4*>(d)[j] = o;
  } else if (bid < 12224) {
    const int row = (bid - 4032) * 4 + (tid >> 6);
    const int lane = tid & 63;
    const float4* xr = reinterpret_cast<const float4*>(seq + (size_t)row * 768);
    float4 v[3];
    #pragma unroll
    for (int j = 0; j < 3; ++j) v[j] = xr[j * 64 + lane];
    float s = 0.f, q = 0.f;
    #pragma unroll
    for (int j = 0; j < 3; ++j) {
      s += v[j].x + v[j].y + v[j].z + v[j].w;
      q += v[j].x * v[j].x + v[j].y * v[j].y + v[j].z * v[j].z + v[j].w * v[j].w;
    }
    wredxor2(s, q);
    float mean = s * (1.0f / 768.0f);
    float rstd = rsqrtf(q * (1.0f / 768.0f) - mean * mean + 1e-5f);
    ushort4* orow = reinterpret_cast<ushort4*>(lnx + (size_t)row * 768);
    #pragma unroll
    for (int j = 0; j < 3; ++j) {
      float4 gv = reinterpret_cast<const float4*>(ate_g)[j * 64 + lane];
      float4 bv = reinterpret_cast<const float4*>(ate_b)[j * 64 + lane];
      ushort4 o;
      o.x = f2b((v[j].x - mean) * rstd * gv.x + bv.x);
      o.y = f2b((v[j].y - mean) * rstd * gv.y + bv.y);
      o.z = f2b((v[j].z - mean) * rstd * gv.z + bv.z);
      o.w = f2b((v[j].w - mean) * rstd * gv.w + bv.w);
      orow[j * 64 + lane] = o;
    }
  } else {
    if (tid >= 192) return;
    int r = bid - 12224;            // 0..3839 = span*15 + w
    int span = r / 15, w = r % 15;
    int s, e, left, right;
    span_params(st, en, span, s, e, left, right);
    int b = span >> 2;
    int tok = min(left + w, 511);
    const float4* src = reinterpret_cast<const float4*>(seq + ((size_t)b * 512 + tok) * 768);
    ushort4* dst = reinterpret_cast<ushort4*>(ctxA + (size_t)r * 768);
    float4 v = src[tid];
    ushort4 o;
    o.x = f2b(v.x); o.y = f2b(v.y); o.z = f2b(v.z); o.w = f2b(v.w);
    dst[tid] = o;
  }
}

// ---------------- MFMA bf16 GEMM body: BK=64, XOR-swizzled LDS, single buffer --------
// LDS layout: elem (row, c) stored at row*64 + (c ^ 8*(row&7)).
// Generalized wave grid: WAVES = (BM/WM)*(BN/WN), blockDim.x = WAVES*64.
template<int BM, int BN, int WM, int WN>
DEVI void gemm_body64(const unsigned short* __restrict__ A,
                      const unsigned short* __restrict__ W,
                      const float* __restrict__ bias, unsigned short* __restrict__ C,
                      int M, int N, int K, bool act, int bm, int bn,
                      unsigned short* As, unsigned short* Bs) {
  constexpr int CA = BM / 8;
  constexpr int CB = BN / 8;
  constexpr int NWC = BN / WN;
  constexpr int WAVES = (BM / WM) * NWC;
  constexpr int FM = WM / 16, FN = WN / 16;
  const int tid = threadIdx.x;
  const int lane = tid & 63;
  const int wv = tid >> 6;
  const int wr = wv / NWC, wc = wv % NWC;
  const int l16 = lane & 15, lhi = lane >> 4;
  const int srow = lane >> 3;
  const int scol = 8 * ((lane & 7) ^ srow);

  f32x4 acc[FM][FN] = {};
  const int nt = K / 64;

  for (int t = 0; t < nt; ++t) {
    const int k0 = t * 64;
    #pragma unroll
    for (int ch = wv; ch < CA; ch += WAVES)
      __builtin_amdgcn_global_load_lds(
          (const __attribute__((address_space(1))) void*)&A[(size_t)(bm + ch * 8 + srow) * K + k0 + scol],
          (__attribute__((address_space(3))) void*)&As[ch * 512], 16, 0, 0);
    #pragma unroll
    for (int ch = wv; ch < CB; ch += WAVES)
      __builtin_amdgcn_global_load_lds(
          (const __attribute__((address_space(1))) void*)&W[(size_t)(bn + ch * 8 + srow) * K + k0 + scol],
          (__attribute__((address_space(3))) void*)&Bs[ch * 512], 16, 0, 0);
    __syncthreads();
    #pragma unroll
    for (int kk = 0; kk < 2; ++kk) {
      bf16x8 af[FM], bfr[FN];
      #pragma unroll
      for (int fm = 0; fm < FM; ++fm) {
        int r = wr * WM + fm * 16 + l16;
        af[fm] = *reinterpret_cast<const bf16x8*>(&As[r * 64 + ((kk * 32 + lhi * 8) ^ ((r & 7) * 8))]);
      }
      #pragma unroll
      for (int fn = 0; fn < FN; ++fn) {
        int r = wc * WN + fn * 16 + l16;
        bfr[fn] = *reinterpret_cast<const bf16x8*>(&Bs[r * 64 + ((kk * 32 + lhi * 8) ^ ((r & 7) * 8))]);
      }
      #pragma unroll
      for (int fm = 0; fm < FM; ++fm)
        #pragma unroll
        for (int fn = 0; fn < FN; ++fn)
          acc[fm][fn] = __builtin_amdgcn_mfma_f32_16x16x32_bf16(af[fm], bfr[fn], acc[fm][fn], 0, 0, 0);
    }
    __syncthreads();
  }

  #pragma unroll
  for (int fm = 0; fm < FM; ++fm) {
    #pragma unroll
    for (int fn = 0; fn < FN; ++fn) {
      int col = bn + wc * WN + fn * 16 + l16;
      float bv = bias[col];
      #pragma unroll
      for (int i = 0; i < 4; ++i) {
        int row = bm + wr * WM + fm * 16 + lhi * 4 + i;
        float v = acc[fm][fn][i] + bv;
        if (act) v = gelu_f(v);
        C[(size_t)row * N + col] = f2b(v);
      }
    }
  }
}

// XCD-swizzled standalone GEMM (BK=64 swizzled body), 4-wave shapes
template<int BM, int BN, int WM, int WN, int ACT>
__global__ __launch_bounds__(256) void gemm_swz64(
    const unsigned short* __restrict__ A, const unsigned short* __restrict__ W,
    const float* __restrict__ bias, unsigned short* __restrict__ C,
    int M, int N, int K, int nbN) {
  __shared__ __align__(16) unsigned short As[BM * 64];
  __shared__ __align__(16) unsigned short Bs[BN * 64];
  int l = xcd_logical(blockIdx.x, gridDim.x);
  int mb = l / nbN, nb = l % nbN;
  gemm_body64<BM, BN, WM, WN>(A, W, bias, C, M, N, K, ACT != 0,
                              mb * BM, nb * BN, As, Bs);
}

// merged independent GEMMs, 8-wave big tiles:
// ATE hidden 256x128 (384 blocks) + qkv 128x256 (270 blocks), XCD-swizzled
__global__ __launch_bounds__(512) void dual_gemm_kernel(
    const unsigned short* __restrict__ lnx, const unsigned short* __restrict__ w1b,
    const float* __restrict__ b1, unsigned short* __restrict__ hate,
    const unsigned short* __restrict__ ctxA, const unsigned short* __restrict__ winb,
    const float* __restrict__ b_in, unsigned short* __restrict__ qkv) {
  __shared__ __align__(16) unsigned short lds[384 * 64];   // 48 KB
  if (blockIdx.x < 384) {
    int l = xcd_logical(blockIdx.x, 384);
    int mb = l / 3, nb = l % 3;                 // 3 nb share the A(lnx) panel
    gemm_body64<256, 128, 64, 64>(lnx, w1b, b1, hate, 32768, 384, 768, true,
                                  mb * 256, nb * 128, lds, lds + 256 * 64);
  } else {
    int bid = blockIdx.x - 384;                 // 384%8==0 keeps alignment
    int l = xcd_logical(bid, 270);
    int mb = l / 9, nb = l % 9;                 // 9 nb share the A(ctxA) panel
    gemm_body64<128, 256, 64, 64>(ctxA, winb, b_in, qkv, 3840, 2304, 768, false,
                                  mb * 128, nb * 256, lds, lds + 128 * 64);
  }
}

// ---------------- merged: ATE head finish (bid<8192) + attention (else) ----------------
__global__ __launch_bounds__(256) void finattn_kernel(
    const unsigned short* __restrict__ h, const float* __restrict__ lng,
    const float* __restrict__ lnb, const float* __restrict__ w2,
    const float* __restrict__ b2, float* __restrict__ out,
    const unsigned short* __restrict__ qkv, const int* __restrict__ st,
    const int* __restrict__ en, unsigned short* __restrict__ ctxO) {
  __shared__ float qs[15][96], ks[15][96], vs[15][96];
  __shared__ float sc[15][16];
  const int tid = threadIdx.x;
  if (blockIdx.x < 8192) {
    const int row = blockIdx.x * 4 + (tid >> 6);
    const int lane = tid & 63;
    const unsigned short* hr = h + (size_t)row * 384 + lane * 6;
    ushort2 u0 = *reinterpret_cast<const ushort2*>(hr);
    ushort2 u1 = *reinterpret_cast<const ushort2*>(hr + 2);
    ushort2 u2 = *reinterpret_cast<const ushort2*>(hr + 4);
    float v[6] = { b2f(u0.x), b2f(u0.y), b2f(u1.x), b2f(u1.y), b2f(u2.x), b2f(u2.y) };
    float s = 0.f, q = 0.f;
    #pragma unroll
    for (int j = 0; j < 6; ++j) { s += v[j]; q += v[j] * v[j]; }
    wredxor2(s, q);
    float mean = s * (1.f / 384.f);
    float rstd = rsqrtf(q * (1.f / 384.f) - mean * mean + 1e-5f);
    const int c0 = lane * 6;
    float p0 = 0.f, p1 = 0.f;
    #pragma unroll
    for (int j = 0; j < 6; ++j) {
      float hl = (v[j] - mean) * rstd * lng[c0 + j] + lnb[c0 + j];
      p0 += hl * w2[c0 + j];
      p1 += hl * w2[384 + c0 + j];
    }
    wredxor2(p0, p1);
    if (lane == 0) {
      out[(size_t)row * 2]     = p0 + b2[0];
      out[(size_t)row * 2 + 1] = p1 + b2[1];
    }
    return;
  }
  const int blk = blockIdx.x - 8192;
  const int span = blk >> 3, hh = blk & 7;
  int s, e, left, right;
  span_params(st, en, span, s, e, left, right);
  const int nv = right - left;
  const int r0 = span * 15;
  const float scale = 0.10206207261596576f;   // 1/sqrt(96)
  if (tid < 180) {
    int w = tid / 12, dp = tid % 12, d = dp * 8;
    const unsigned short* rowp = qkv + (size_t)(r0 + w) * 2304 + hh * 96 + d;
    bf16x8 qv = *reinterpret_cast<const bf16x8*>(rowp);
    bf16x8 kv = *reinterpret_cast<const bf16x8*>(rowp + 768);
    bf16x8 vv = *reinterpret_cast<const bf16x8*>(rowp + 1536);
    #pragma unroll
    for (int j = 0; j < 8; ++j) {
      qs[w][d + j] = b2f((unsigned short)qv[j]) * scale;
      ks[w][d + j] = b2f((unsigned short)kv[j]);
      vs[w][d + j] = b2f((unsigned short)vv[j]);
    }
  }
  __syncthreads();
  if (tid < 225) {
    int i = tid / 15, j = tid % 15;
    float a = 0.f;
    #pragma unroll
    for (int d = 0; d < 96; ++d) a += qs[i][d] * ks[j][d];
    sc[i][j] = (j < nv) ? a : -3.402823466e38f;
  }
  __syncthreads();
  if (tid < 15) {
    int i = tid;
    float m = -3.402823466e38f;
    #pragma unroll
    for (int j = 0; j < 15; ++j) m = fmaxf(m, sc[i][j]);
    float ex[15];
    float ssum = 0.f;
    #pragma unroll
    for (int j = 0; j < 15; ++j) { ex[j] = expf(sc[i][j] - m); ssum += ex[j]; }
    float inv = 1.0f / ssum;
    #pragma unroll
    for (int j = 0; j < 15; ++j) sc[i][j] = ex[j] * inv;
  }
  __syncthreads();
  for (int idx = tid; idx < 720; idx += 256) {
    int w = idx / 48, dp = idx % 48, d = dp * 2;
    float o0 = 0.f, o1 = 0.f;
    #pragma unroll
    for (int j = 0; j < 15; ++j) {
      float p = sc[w][j];
      o0 += p * vs[j][d];
      o1 += p * vs[j][d + 1];
    }
    ushort2 o; o.x = f2b(o0); o.y = f2b(o1);
    *reinterpret_cast<ushort2*>(&ctxO[(size_t)(r0 + w) * 768 + hh * 96 + d]) = o;
  }
}

// ---------------- masked means -> combined[span][0:768]=asp, [768:1536]=ctx ----------------
__global__ __launch_bounds__(256) void means_kernel(
    const float* __restrict__ seq, const unsigned short* __restrict__ projO,
    const int* __restrict__ st, const int* __restrict__ en,
    unsigned short* __restrict__ comb) {
  const int span = blockIdx.x;
  int s, e, left, right;
  span_params(st, en, span, s, e, left, right);
  int b = span >> 2;
  int e2 = min(e, s + 8);
  int cnt = e2 - s;
  int nv = right - left;
  float inva = (cnt > 0) ? 1.0f / (float)cnt : 0.f;
  float invc = 1.0f / (float)nv;
  for (int c = threadIdx.x; c < 768; c += 256) {
    float sa = 0.f;
    for (int t = s; t < e2; ++t) sa += seq[((size_t)b * 512 + t) * 768 + c];
    float asp = (cnt > 0) ? sa * inva : seq[((size_t)b * 512) * 768 + c];
    comb[(size_t)span * 1536 + c] = f2b(asp);
    float sc_ = 0.f;
    for (int w = 0; w < nv; ++w) sc_ += b2f(projO[(size_t)(span * 15 + w) * 768 + c]);
    comb[(size_t)span * 1536 + 768 + c] = f2b(sc_ * invc);
  }
}

// ---------------- APC all-in-one: span-mean -> LN -> hidden GEMV -> LN -> head ---------
__global__ __launch_bounds__(256) void apc_all_kernel(
    const unsigned short* __restrict__ fused, const float* __restrict__ g,
    const float* __restrict__ bb, const unsigned short* __restrict__ senb,
    const float* __restrict__ b1, const float* __restrict__ lng,
    const float* __restrict__ lnb, const float* __restrict__ w2,
    const float* __restrict__ b2, float* __restrict__ out) {
  const int b = blockIdx.x, tid = threadIdx.x;
  __shared__ float xs[768];
  __shared__ float hs[384];
  float v[3];
  #pragma unroll
  for (int j = 0; j < 3; ++j) {
    int c = tid + j * 256;
    float a = 0.f;
    #pragma unroll
    for (int n = 0; n < 4; ++n) a += b2f(fused[((size_t)(b * 4 + n)) * 768 + c]);
    v[j] = 0.25f * a;
  }
  float s = v[0] + v[1] + v[2];
  float q = v[0] * v[0] + v[1] * v[1] + v[2] * v[2];
  breduce2<4>(s, q);
  float mean = s * (1.f / 768.f);
  float rstd = rsqrtf(q * (1.f / 768.f) - mean * mean + 1e-5f);
  #pragma unroll
  for (int j = 0; j < 3; ++j) {
    int c = tid + j * 256;
    xs[c] = (v[j] - mean) * rstd * g[c] + bb[c];
  }
  __syncthreads();
  for (int j = tid; j < 384; j += 256) {
    const bf16x8* wrp = reinterpret_cast<const bf16x8*>(senb + (size_t)j * 768);
    float dot = 0.f;
    #pragma unroll 4
    for (int k8 = 0; k8 < 96; ++k8) {
      bf16x8 wv = wrp[k8];
      #pragma unroll
      for (int u = 0; u < 8; ++u) dot += xs[k8 * 8 + u] * b2f((unsigned short)wv[u]);
    }
    hs[j] = gelu_f(dot + b1[j]);
  }
  __syncthreads();
  s = 0.f; q = 0.f;
  for (int j = tid; j < 384; j += 256) { float h = hs[j]; s += h; q += h * h; }
  breduce2<4>(s, q);
  mean = s * (1.f / 384.f);
  rstd = rsqrtf(q * (1.f / 384.f) - mean * mean + 1e-5f);
  float p0 = 0.f, p1 = 0.f;
  for (int j = tid; j < 384; j += 256) {
    float hl = (hs[j] - mean) * rstd * lng[j] + lnb[j];
    p0 += hl * w2[j];
    p1 += hl * w2[384 + j];
  }
  breduce2<4>(p0, p1);
  if (tid == 0) {
    out[b * 2]     = p0 + b2[0];
    out[b * 2 + 1] = p1 + b2[1];
  }
}

extern "C" void kernel_launch(void* const* d_in, const int* in_sizes, int n_in,
                              void* d_out, int out_size, void* d_ws, size_t ws_size,
                              hipStream_t stream) {
  const float* seq    = (const float*)d_in[0];
  const int*   st     = (const int*)d_in[1];
  const int*   en     = (const int*)d_in[2];
  const float* ate_g  = (const float*)d_in[3];
  const float* ate_b  = (const float*)d_in[4];
  const float* apc_g  = (const float*)d_in[5];
  const float* apc_b  = (const float*)d_in[6];
  const float* w_in   = (const float*)d_in[7];
  const float* b_in   = (const float*)d_in[8];
  const float* w_out  = (const float*)d_in[9];
  const float* b_out  = (const float*)d_in[10];
  const float* fus_w  = (const float*)d_in[11];
  const float* fus_b  = (const float*)d_in[12];
  const float* asp_w1 = (const float*)d_in[13];
  const float* asp_b1 = (const float*)d_in[14];
  const float* asp_lng= (const float*)d_in[15];
  const float* asp_lnb= (const float*)d_in[16];
  const float* asp_w2 = (const float*)d_in[17];
  const float* asp_b2 = (const float*)d_in[18];
  const float* sen_w1 = (const float*)d_in[19];
  const float* sen_b1 = (const float*)d_in[20];
  const float* sen_lng= (const float*)d_in[21];
  const float* sen_lnb= (const float*)d_in[22];
  const float* sen_w2 = (const float*)d_in[23];
  const float* sen_b2 = (const float*)d_in[24];
  float* out = (float*)d_out;

  char* wsb = (char*)d_ws;
  unsigned short* lnx   = (unsigned short*)(wsb + 0);          // 32768x768 bf16
  unsigned short* ctxA  = (unsigned short*)(wsb + 52428800);   // 3840x768
  unsigned short* qkvb  = (unsigned short*)(wsb + 58720256);   // 3840x2304
  unsigned short* ctxO  = (unsigned short*)(wsb + 77594624);   // 3840x768
  unsigned short* projO = (unsigned short*)(wsb + 83886080);   // 3840x768
  unsigned short* comb  = (unsigned short*)(wsb + 89849856);   // 256x1536
  unsigned short* fusO  = (unsigned short*)(wsb + 90636288);   // 256x768
  const size_t off_w = 91275264;
  unsigned short* hate  = (unsigned short*)(wsb + off_w);             // 32768x384
  const size_t off_w2 = off_w + 25165824;
  unsigned short* w1b   = (unsigned short*)(wsb + off_w2);            // 384x768
  unsigned short* winb  = (unsigned short*)(wsb + off_w2 + 589824);   // 2304x768
  unsigned short* woutb = (unsigned short*)(wsb + off_w2 + 4128768);  // 768x768
  unsigned short* fusb  = (unsigned short*)(wsb + off_w2 + 5308416);  // 768x1536
  unsigned short* senb  = (unsigned short*)(wsb + off_w2 + 7667712);  // 384x768

  // 1) prep: cvt + ln_seq + gather
  prep_kernel<<<16064, 256, 0, stream>>>(asp_w1, w_in, w_out, fus_w, sen_w1,
                                         w1b, winb, woutb, fusb, senb,
                                         seq, ate_g, ate_b, lnx, st, en, ctxA);
  // 2) ATE hidden GEMM (256x128) + qkv GEMM (128x256) merged, 8-wave, XCD-swizzled
  dual_gemm_kernel<<<654, 512, 0, stream>>>(lnx, w1b, asp_b1, hate,
                                            ctxA, winb, b_in, qkvb);
  // 3) ATE head finish + attention merged
  finattn_kernel<<<10240, 256, 0, stream>>>(hate, asp_lng, asp_lnb, asp_w2, asp_b2, out,
                                            qkvb, st, en, ctxO);
  // 4) proj GEMM (BM=64: 60 mb x 6 nb = 360 blocks)
  gemm_swz64<64, 128, 32, 64, 0><<<360, 256, 0, stream>>>(
      ctxO, woutb, b_out, projO, 3840, 768, 768, 6);
  // 5) masked means
  means_kernel<<<256, 256, 0, stream>>>(seq, projO, st, en, comb);
  // 6) fusion GEMM (BM=BN=64: 4 mb x 12 nb = 48 blocks)
  gemm_swz64<64, 64, 32, 32, 1><<<48, 256, 0, stream>>>(
      comb, fusb, fus_b, fusO, 256, 768, 1536, 12);
  // 7) APC all-in-one
  apc_all_kernel<<<64, 256, 0, stream>>>(fusO, apc_g, apc_b, senb, sen_b1,
                                         sen_lng, sen_lnb, sen_w2, sen_b2, out + 65536);
}

// Round 10
// 183.240 us; speedup vs baseline: 1.5234x; 1.0261x over previous
//
#include <hip/hip_runtime.h>
#include <math.h>

#define DEVI __device__ __forceinline__

using bf16x8 = __attribute__((ext_vector_type(8))) short;
using f32x4  = __attribute__((ext_vector_type(4))) float;

DEVI float b2f(unsigned short u) {
  union { unsigned int u; float f; } x; x.u = ((unsigned int)u) << 16; return x.f;
}
DEVI unsigned short f2b(float f) {
  union { float f; unsigned int u; } x; x.f = f;
  unsigned int r = (x.u + 0x7fffu + ((x.u >> 16) & 1u)) >> 16;
  return (unsigned short)r;
}
DEVI float gelu_f(float x) { return 0.5f * x * (1.0f + erff(x * 0.70710678118654752440f)); }

DEVI void wredxor2(float& a, float& b) {
  #pragma unroll
  for (int off = 32; off; off >>= 1) {
    a += __shfl_xor(a, off);
    b += __shfl_xor(b, off);
  }
}

template<int NW>
DEVI void breduce2(float& a, float& b) {
  __shared__ float buf[2 * NW];
  int lane = threadIdx.x & 63;
  int w = threadIdx.x >> 6;
  #pragma unroll
  for (int off = 32; off > 0; off >>= 1) {
    a += __shfl_down(a, off);
    b += __shfl_down(b, off);
  }
  if (lane == 0) { buf[w] = a; buf[NW + w] = b; }
  __syncthreads();
  float ra = 0.f, rb = 0.f;
  #pragma unroll
  for (int i = 0; i < NW; ++i) { ra += buf[i]; rb += buf[NW + i]; }
  a = ra; b = rb;
  __syncthreads();
}

DEVI void span_params(const int* st, const int* en, int span,
                      int& s, int& e, int& left, int& right) {
  int s0 = st[span], e0 = en[span];
  s = min(max(s0, 0), 511);
  e = max(s, min(e0, 511));
  left = max(0, s - 3);
  right = min(512, e + 4);
}

// bijective XCD chunk transform (m204)
DEVI int xcd_logical(int bid, int n) {
  int q = n >> 3, r = n & 7;
  int xcd = bid & 7, idx = bid >> 3;
  return (xcd < r ? xcd * (q + 1) : r * (q + 1) + (xcd - r) * q) + idx;
}

// ---------------- fused prep: weight cvt + seq LayerNorm + ctx gather ----------------
__global__ __launch_bounds__(256) void prep_kernel(
    const float* __restrict__ s0, const float* __restrict__ s1,
    const float* __restrict__ s2, const float* __restrict__ s3,
    const float* __restrict__ s4,
    unsigned short* __restrict__ d0, unsigned short* __restrict__ d1,
    unsigned short* __restrict__ d2, unsigned short* __restrict__ d3,
    unsigned short* __restrict__ d4,
    const float* __restrict__ seq, const float* __restrict__ ate_g,
    const float* __restrict__ ate_b, unsigned short* __restrict__ lnx,
    const int* __restrict__ st, const int* __restrict__ en,
    unsigned short* __restrict__ ctxA) {
  const int bid = blockIdx.x, tid = threadIdx.x;
  if (bid < 4032) {
    int i = bid * 256 + tid;
    const float* s; unsigned short* d; int j;
    if (i < 73728)       { s = s0; d = d0; j = i; }
    else if (i < 516096) { s = s1; d = d1; j = i - 73728; }
    else if (i < 663552) { s = s2; d = d2; j = i - 516096; }
    else if (i < 958464) { s = s3; d = d3; j = i - 663552; }
    else                 { s = s4; d = d4; j = i - 958464; }
    float4 v = reinterpret_cast<const float4*>(s)[j];
    ushort4 o;
    o.x = f2b(v.x); o.y = f2b(v.y); o.z = f2b(v.z); o.w = f2b(v.w);
    reinterpret_cast<ushort4*>(d)[j] = o;
  } else if (bid < 12224) {
    const int row = (bid - 4032) * 4 + (tid >> 6);
    const int lane = tid & 63;
    const float4* xr = reinterpret_cast<const float4*>(seq + (size_t)row * 768);
    float4 v[3];
    #pragma unroll
    for (int j = 0; j < 3; ++j) v[j] = xr[j * 64 + lane];
    float s = 0.f, q = 0.f;
    #pragma unroll
    for (int j = 0; j < 3; ++j) {
      s += v[j].x + v[j].y + v[j].z + v[j].w;
      q += v[j].x * v[j].x + v[j].y * v[j].y + v[j].z * v[j].z + v[j].w * v[j].w;
    }
    wredxor2(s, q);
    float mean = s * (1.0f / 768.0f);
    float rstd = rsqrtf(q * (1.0f / 768.0f) - mean * mean + 1e-5f);
    ushort4* orow = reinterpret_cast<ushort4*>(lnx + (size_t)row * 768);
    #pragma unroll
    for (int j = 0; j < 3; ++j) {
      float4 gv = reinterpret_cast<const float4*>(ate_g)[j * 64 + lane];
      float4 bv = reinterpret_cast<const float4*>(ate_b)[j * 64 + lane];
      ushort4 o;
      o.x = f2b((v[j].x - mean) * rstd * gv.x + bv.x);
      o.y = f2b((v[j].y - mean) * rstd * gv.y + bv.y);
      o.z = f2b((v[j].z - mean) * rstd * gv.z + bv.z);
      o.w = f2b((v[j].w - mean) * rstd * gv.w + bv.w);
      orow[j * 64 + lane] = o;
    }
  } else {
    if (tid >= 192) return;
    int r = bid - 12224;            // 0..3839 = span*15 + w
    int span = r / 15, w = r % 15;
    int s, e, left, right;
    span_params(st, en, span, s, e, left, right);
    int b = span >> 2;
    int tok = min(left + w, 511);
    const float4* src = reinterpret_cast<const float4*>(seq + ((size_t)b * 512 + tok) * 768);
    ushort4* dst = reinterpret_cast<ushort4*>(ctxA + (size_t)r * 768);
    float4 v = src[tid];
    ushort4 o;
    o.x = f2b(v.x); o.y = f2b(v.y); o.z = f2b(v.z); o.w = f2b(v.w);
    dst[tid] = o;
  }
}

// ---------------- MFMA bf16 GEMM core: BK=64, XOR-swizzled LDS, single buffer --------
// LDS layout: elem (row, c) stored at row*64 + (c ^ 8*(row&7)).
template<int BM, int BN, int WM, int WN>
DEVI void gemm_core(const unsigned short* __restrict__ A,
                    const unsigned short* __restrict__ W,
                    int K, int bm, int bn,
                    unsigned short* As, unsigned short* Bs,
                    f32x4 (&acc)[WM / 16][WN / 16]) {
  constexpr int CA = BM / 8;
  constexpr int CB = BN / 8;
  constexpr int NWC = BN / WN;
  constexpr int WAVES = (BM / WM) * NWC;
  constexpr int FM = WM / 16, FN = WN / 16;
  const int tid = threadIdx.x;
  const int lane = tid & 63;
  const int wv = tid >> 6;
  const int wr = wv / NWC, wc = wv % NWC;
  const int l16 = lane & 15, lhi = lane >> 4;
  const int srow = lane >> 3;
  const int scol = 8 * ((lane & 7) ^ srow);

  const int nt = K / 64;
  for (int t = 0; t < nt; ++t) {
    const int k0 = t * 64;
    #pragma unroll
    for (int ch = wv; ch < CA; ch += WAVES)
      __builtin_amdgcn_global_load_lds(
          (const __attribute__((address_space(1))) void*)&A[(size_t)(bm + ch * 8 + srow) * K + k0 + scol],
          (__attribute__((address_space(3))) void*)&As[ch * 512], 16, 0, 0);
    #pragma unroll
    for (int ch = wv; ch < CB; ch += WAVES)
      __builtin_amdgcn_global_load_lds(
          (const __attribute__((address_space(1))) void*)&W[(size_t)(bn + ch * 8 + srow) * K + k0 + scol],
          (__attribute__((address_space(3))) void*)&Bs[ch * 512], 16, 0, 0);
    __syncthreads();
    #pragma unroll
    for (int kk = 0; kk < 2; ++kk) {
      bf16x8 af[FM], bfr[FN];
      #pragma unroll
      for (int fm = 0; fm < FM; ++fm) {
        int r = wr * WM + fm * 16 + l16;
        af[fm] = *reinterpret_cast<const bf16x8*>(&As[r * 64 + ((kk * 32 + lhi * 8) ^ ((r & 7) * 8))]);
      }
      #pragma unroll
      for (int fn = 0; fn < FN; ++fn) {
        int r = wc * WN + fn * 16 + l16;
        bfr[fn] = *reinterpret_cast<const bf16x8*>(&Bs[r * 64 + ((kk * 32 + lhi * 8) ^ ((r & 7) * 8))]);
      }
      #pragma unroll
      for (int fm = 0; fm < FM; ++fm)
        #pragma unroll
        for (int fn = 0; fn < FN; ++fn)
          acc[fm][fn] = __builtin_amdgcn_mfma_f32_16x16x32_bf16(af[fm], bfr[fn], acc[fm][fn], 0, 0, 0);
    }
    __syncthreads();
  }
}

// standard epilogue: bias (+gelu) -> bf16 store
template<int BM, int BN, int WM, int WN>
DEVI void gemm_store(const float* __restrict__ bias, unsigned short* __restrict__ C,
                     int N, bool act, int bm, int bn, f32x4 (&acc)[WM / 16][WN / 16]) {
  constexpr int NWC = BN / WN;
  constexpr int FM = WM / 16, FN = WN / 16;
  const int lane = threadIdx.x & 63;
  const int wv = threadIdx.x >> 6;
  const int wr = wv / NWC, wc = wv % NWC;
  const int l16 = lane & 15, lhi = lane >> 4;
  #pragma unroll
  for (int fm = 0; fm < FM; ++fm) {
    #pragma unroll
    for (int fn = 0; fn < FN; ++fn) {
      int col = bn + wc * WN + fn * 16 + l16;
      float bv = bias[col];
      #pragma unroll
      for (int i = 0; i < 4; ++i) {
        int row = bm + wr * WM + fm * 16 + lhi * 4 + i;
        float v = acc[fm][fn][i] + bv;
        if (act) v = gelu_f(v);
        C[(size_t)row * N + col] = f2b(v);
      }
    }
  }
}

// XCD-swizzled standalone GEMM
template<int BM, int BN, int WM, int WN, int ACT>
__global__ __launch_bounds__(256) void gemm_swz64(
    const unsigned short* __restrict__ A, const unsigned short* __restrict__ W,
    const float* __restrict__ bias, unsigned short* __restrict__ C,
    int M, int N, int K, int nbN) {
  __shared__ __align__(16) unsigned short As[BM * 64];
  __shared__ __align__(16) unsigned short Bs[BN * 64];
  int l = xcd_logical(blockIdx.x, gridDim.x);
  int mb = l / nbN, nb = l % nbN;
  f32x4 acc[WM / 16][WN / 16] = {};
  gemm_core<BM, BN, WM, WN>(A, W, K, mb * BM, nb * BN, As, Bs, acc);
  gemm_store<BM, BN, WM, WN>(bias, C, N, ACT != 0, mb * BM, nb * BN, acc);
}

// merged GEMMs: ATE hidden 256x128 (384 blocks, head-partial epilogue)
//              + qkv 128x256 (270 blocks, normal epilogue)
// hpart[row][p] = float4(sum h, sum h^2, sum h*g*w2a, sum h*g*w2b), p = nb*2+wc
__global__ __launch_bounds__(512) void dual_gemm_kernel(
    const unsigned short* __restrict__ lnx, const unsigned short* __restrict__ w1b,
    const float* __restrict__ b1, const float* __restrict__ lng,
    const float* __restrict__ w2, float4* __restrict__ hpart,
    const unsigned short* __restrict__ ctxA, const unsigned short* __restrict__ winb,
    const float* __restrict__ b_in, unsigned short* __restrict__ qkv) {
  __shared__ __align__(16) unsigned short lds[384 * 64];   // 48 KB
  if (blockIdx.x < 384) {
    int l = xcd_logical(blockIdx.x, 384);
    int mb = l / 3, nb = l % 3;
    const int bm = mb * 256, bn = nb * 128;
    f32x4 acc[4][4] = {};
    gemm_core<256, 128, 64, 64>(lnx, w1b, 768, bm, bn, lds, lds + 256 * 64, acc);
    // head-partial epilogue
    const int lane = threadIdx.x & 63;
    const int wv = threadIdx.x >> 6;
    const int wr = wv >> 1, wc = wv & 1;        // NWC=2
    const int l16 = lane & 15, lhi = lane >> 4;
    float b1v[4], gw2a[4], gw2b[4];
    #pragma unroll
    for (int fn = 0; fn < 4; ++fn) {
      int col = bn + wc * 64 + fn * 16 + l16;
      b1v[fn] = b1[col];
      float gg = lng[col];
      gw2a[fn] = gg * w2[col];
      gw2b[fn] = gg * w2[384 + col];
    }
    #pragma unroll
    for (int fm = 0; fm < 4; ++fm) {
      #pragma unroll
      for (int i = 0; i < 4; ++i) {
        float s1 = 0.f, s2 = 0.f, q0 = 0.f, q1 = 0.f;
        #pragma unroll
        for (int fn = 0; fn < 4; ++fn) {
          float h = gelu_f(acc[fm][fn][i] + b1v[fn]);
          s1 += h; s2 += h * h;
          q0 += h * gw2a[fn]; q1 += h * gw2b[fn];
        }
        #pragma unroll
        for (int off = 1; off < 16; off <<= 1) {
          s1 += __shfl_xor(s1, off); s2 += __shfl_xor(s2, off);
          q0 += __shfl_xor(q0, off); q1 += __shfl_xor(q1, off);
        }
        if (l16 == 0) {
          int row = bm + wr * 64 + fm * 16 + lhi * 4 + i;
          hpart[(size_t)row * 6 + nb * 2 + wc] = make_float4(s1, s2, q0, q1);
        }
      }
    }
  } else {
    int bid = blockIdx.x - 384;
    int l = xcd_logical(bid, 270);
    int mb = l / 9, nb = l % 9;
    f32x4 acc[4][4] = {};
    gemm_core<128, 256, 64, 64>(ctxA, winb, 768, mb * 128, nb * 256,
                                lds, lds + 128 * 64, acc);
    gemm_store<128, 256, 64, 64>(b_in, qkv, 2304, false, mb * 128, nb * 256, acc);
  }
}

// ---------------- merged: attention (bid<2048) + ATE head finish from partials -------
__global__ __launch_bounds__(256) void finattn_kernel(
    const float4* __restrict__ hpart, const float* __restrict__ lng,
    const float* __restrict__ lnb, const float* __restrict__ w2,
    const float* __restrict__ b2, float* __restrict__ out,
    const unsigned short* __restrict__ qkv, const int* __restrict__ st,
    const int* __restrict__ en, unsigned short* __restrict__ ctxO) {
  const int tid = threadIdx.x;
  if (blockIdx.x >= 2048) {
    // ATE finish: p = rstd*(D - mu*C1) + C2 + b2  (exact algebra of LN+linear head)
    __shared__ float cbuf[16];
    float c1a = 0.f, c1b = 0.f, c2a = 0.f, c2b = 0.f;
    for (int c = tid; c < 384; c += 256) {
      float gg = lng[c], bbv = lnb[c], wa = w2[c], wb = w2[384 + c];
      c1a += gg * wa; c1b += gg * wb;
      c2a += bbv * wa; c2b += bbv * wb;
    }
    wredxor2(c1a, c1b);
    wredxor2(c2a, c2b);
    if ((tid & 63) == 0) {
      int w = tid >> 6;
      cbuf[w * 4] = c1a; cbuf[w * 4 + 1] = c1b;
      cbuf[w * 4 + 2] = c2a; cbuf[w * 4 + 3] = c2b;
    }
    __syncthreads();
    c1a = cbuf[0] + cbuf[4] + cbuf[8] + cbuf[12];
    c1b = cbuf[1] + cbuf[5] + cbuf[9] + cbuf[13];
    c2a = cbuf[2] + cbuf[6] + cbuf[10] + cbuf[14];
    c2b = cbuf[3] + cbuf[7] + cbuf[11] + cbuf[15];
    const int row = (blockIdx.x - 2048) * 256 + tid;
    float S1 = 0.f, S2 = 0.f, D0 = 0.f, D1 = 0.f;
    #pragma unroll
    for (int p = 0; p < 6; ++p) {
      float4 v = hpart[(size_t)row * 6 + p];
      S1 += v.x; S2 += v.y; D0 += v.z; D1 += v.w;
    }
    float mu = S1 * (1.f / 384.f);
    float rstd = rsqrtf(S2 * (1.f / 384.f) - mu * mu + 1e-5f);
    out[(size_t)row * 2]     = rstd * (D0 - mu * c1a) + c2a + b2[0];
    out[(size_t)row * 2 + 1] = rstd * (D1 - mu * c1b) + c2b + b2[1];
    return;
  }
  __shared__ float qs[15][96], ks[15][96], vs[15][96];
  __shared__ float sc[15][16];
  const int span = blockIdx.x >> 3, hh = blockIdx.x & 7;
  int s, e, left, right;
  span_params(st, en, span, s, e, left, right);
  const int nv = right - left;
  const int r0 = span * 15;
  const float scale = 0.10206207261596576f;   // 1/sqrt(96)
  if (tid < 180) {
    int w = tid / 12, dp = tid % 12, d = dp * 8;
    const unsigned short* rowp = qkv + (size_t)(r0 + w) * 2304 + hh * 96 + d;
    bf16x8 qv = *reinterpret_cast<const bf16x8*>(rowp);
    bf16x8 kv = *reinterpret_cast<const bf16x8*>(rowp + 768);
    bf16x8 vv = *reinterpret_cast<const bf16x8*>(rowp + 1536);
    #pragma unroll
    for (int j = 0; j < 8; ++j) {
      qs[w][d + j] = b2f((unsigned short)qv[j]) * scale;
      ks[w][d + j] = b2f((unsigned short)kv[j]);
      vs[w][d + j] = b2f((unsigned short)vv[j]);
    }
  }
  __syncthreads();
  if (tid < 225) {
    int i = tid / 15, j = tid % 15;
    float a = 0.f;
    #pragma unroll
    for (int d = 0; d < 96; ++d) a += qs[i][d] * ks[j][d];
    sc[i][j] = (j < nv) ? a : -3.402823466e38f;
  }
  __syncthreads();
  if (tid < 15) {
    int i = tid;
    float m = -3.402823466e38f;
    #pragma unroll
    for (int j = 0; j < 15; ++j) m = fmaxf(m, sc[i][j]);
    float ex[15];
    float ssum = 0.f;
    #pragma unroll
    for (int j = 0; j < 15; ++j) { ex[j] = expf(sc[i][j] - m); ssum += ex[j]; }
    float inv = 1.0f / ssum;
    #pragma unroll
    for (int j = 0; j < 15; ++j) sc[i][j] = ex[j] * inv;
  }
  __syncthreads();
  for (int idx = tid; idx < 720; idx += 256) {
    int w = idx / 48, dp = idx % 48, d = dp * 2;
    float o0 = 0.f, o1 = 0.f;
    #pragma unroll
    for (int j = 0; j < 15; ++j) {
      float p = sc[w][j];
      o0 += p * vs[j][d];
      o1 += p * vs[j][d + 1];
    }
    ushort2 o; o.x = f2b(o0); o.y = f2b(o1);
    *reinterpret_cast<ushort2*>(&ctxO[(size_t)(r0 + w) * 768 + hh * 96 + d]) = o;
  }
}

// ---------------- masked means -> combined[span][0:768]=asp, [768:1536]=ctx ----------------
__global__ __launch_bounds__(256) void means_kernel(
    const float* __restrict__ seq, const unsigned short* __restrict__ projO,
    const int* __restrict__ st, const int* __restrict__ en,
    unsigned short* __restrict__ comb) {
  const int span = blockIdx.x;
  int s, e, left, right;
  span_params(st, en, span, s, e, left, right);
  int b = span >> 2;
  int e2 = min(e, s + 8);
  int cnt = e2 - s;
  int nv = right - left;
  float inva = (cnt > 0) ? 1.0f / (float)cnt : 0.f;
  float invc = 1.0f / (float)nv;
  for (int c = threadIdx.x; c < 768; c += 256) {
    float sa = 0.f;
    for (int t = s; t < e2; ++t) sa += seq[((size_t)b * 512 + t) * 768 + c];
    float asp = (cnt > 0) ? sa * inva : seq[((size_t)b * 512) * 768 + c];
    comb[(size_t)span * 1536 + c] = f2b(asp);
    float sc_ = 0.f;
    for (int w = 0; w < nv; ++w) sc_ += b2f(projO[(size_t)(span * 15 + w) * 768 + c]);
    comb[(size_t)span * 1536 + 768 + c] = f2b(sc_ * invc);
  }
}

// ---------------- APC all-in-one: span-mean -> LN -> hidden GEMV -> LN -> head ---------
__global__ __launch_bounds__(256) void apc_all_kernel(
    const unsigned short* __restrict__ fused, const float* __restrict__ g,
    const float* __restrict__ bb, const unsigned short* __restrict__ senb,
    const float* __restrict__ b1, const float* __restrict__ lng,
    const float* __restrict__ lnb, const float* __restrict__ w2,
    const float* __restrict__ b2, float* __restrict__ out) {
  const int b = blockIdx.x, tid = threadIdx.x;
  __shared__ float xs[768];
  __shared__ float hs[384];
  float v[3];
  #pragma unroll
  for (int j = 0; j < 3; ++j) {
    int c = tid + j * 256;
    float a = 0.f;
    #pragma unroll
    for (int n = 0; n < 4; ++n) a += b2f(fused[((size_t)(b * 4 + n)) * 768 + c]);
    v[j] = 0.25f * a;
  }
  float s = v[0] + v[1] + v[2];
  float q = v[0] * v[0] + v[1] * v[1] + v[2] * v[2];
  breduce2<4>(s, q);
  float mean = s * (1.f / 768.f);
  float rstd = rsqrtf(q * (1.f / 768.f) - mean * mean + 1e-5f);
  #pragma unroll
  for (int j = 0; j < 3; ++j) {
    int c = tid + j * 256;
    xs[c] = (v[j] - mean) * rstd * g[c] + bb[c];
  }
  __syncthreads();
  for (int j = tid; j < 384; j += 256) {
    const bf16x8* wrp = reinterpret_cast<const bf16x8*>(senb + (size_t)j * 768);
    float dot = 0.f;
    #pragma unroll 4
    for (int k8 = 0; k8 < 96; ++k8) {
      bf16x8 wv = wrp[k8];
      #pragma unroll
      for (int u = 0; u < 8; ++u) dot += xs[k8 * 8 + u] * b2f((unsigned short)wv[u]);
    }
    hs[j] = gelu_f(dot + b1[j]);
  }
  __syncthreads();
  s = 0.f; q = 0.f;
  for (int j = tid; j < 384; j += 256) { float h = hs[j]; s += h; q += h * h; }
  breduce2<4>(s, q);
  mean = s * (1.f / 384.f);
  rstd = rsqrtf(q * (1.f / 384.f) - mean * mean + 1e-5f);
  float p0 = 0.f, p1 = 0.f;
  for (int j = tid; j < 384; j += 256) {
    float hl = (hs[j] - mean) * rstd * lng[j] + lnb[j];
    p0 += hl * w2[j];
    p1 += hl * w2[384 + j];
  }
  breduce2<4>(p0, p1);
  if (tid == 0) {
    out[b * 2]     = p0 + b2[0];
    out[b * 2 + 1] = p1 + b2[1];
  }
}

extern "C" void kernel_launch(void* const* d_in, const int* in_sizes, int n_in,
                              void* d_out, int out_size, void* d_ws, size_t ws_size,
                              hipStream_t stream) {
  const float* seq    = (const float*)d_in[0];
  const int*   st     = (const int*)d_in[1];
  const int*   en     = (const int*)d_in[2];
  const float* ate_g  = (const float*)d_in[3];
  const float* ate_b  = (const float*)d_in[4];
  const float* apc_g  = (const float*)d_in[5];
  const float* apc_b  = (const float*)d_in[6];
  const float* w_in   = (const float*)d_in[7];
  const float* b_in   = (const float*)d_in[8];
  const float* w_out  = (const float*)d_in[9];
  const float* b_out  = (const float*)d_in[10];
  const float* fus_w  = (const float*)d_in[11];
  const float* fus_b  = (const float*)d_in[12];
  const float* asp_w1 = (const float*)d_in[13];
  const float* asp_b1 = (const float*)d_in[14];
  const float* asp_lng= (const float*)d_in[15];
  const float* asp_lnb= (const float*)d_in[16];
  const float* asp_w2 = (const float*)d_in[17];
  const float* asp_b2 = (const float*)d_in[18];
  const float* sen_w1 = (const float*)d_in[19];
  const float* sen_b1 = (const float*)d_in[20];
  const float* sen_lng= (const float*)d_in[21];
  const float* sen_lnb= (const float*)d_in[22];
  const float* sen_w2 = (const float*)d_in[23];
  const float* sen_b2 = (const float*)d_in[24];
  float* out = (float*)d_out;

  char* wsb = (char*)d_ws;
  unsigned short* lnx   = (unsigned short*)(wsb + 0);          // 32768x768 bf16
  unsigned short* ctxA  = (unsigned short*)(wsb + 52428800);   // 3840x768
  unsigned short* qkvb  = (unsigned short*)(wsb + 58720256);   // 3840x2304
  unsigned short* ctxO  = (unsigned short*)(wsb + 77594624);   // 3840x768
  unsigned short* projO = (unsigned short*)(wsb + 83886080);   // 3840x768
  unsigned short* comb  = (unsigned short*)(wsb + 89849856);   // 256x1536
  unsigned short* fusO  = (unsigned short*)(wsb + 90636288);   // 256x768
  const size_t off_w = 91275264;
  float4*        hpart  = (float4*)(wsb + off_w);                     // 32768x6 float4 (3MB)
  const size_t off_w2 = off_w + 25165824;
  unsigned short* w1b   = (unsigned short*)(wsb + off_w2);            // 384x768
  unsigned short* winb  = (unsigned short*)(wsb + off_w2 + 589824);   // 2304x768
  unsigned short* woutb = (unsigned short*)(wsb + off_w2 + 4128768);  // 768x768
  unsigned short* fusb  = (unsigned short*)(wsb + off_w2 + 5308416);  // 768x1536
  unsigned short* senb  = (unsigned short*)(wsb + off_w2 + 7667712);  // 384x768

  // 1) prep: cvt + ln_seq + gather
  prep_kernel<<<16064, 256, 0, stream>>>(asp_w1, w_in, w_out, fus_w, sen_w1,
                                         w1b, winb, woutb, fusb, senb,
                                         seq, ate_g, ate_b, lnx, st, en, ctxA);
  // 2) ATE hidden GEMM (256x128, head-partial epilogue) + qkv GEMM (128x256)
  dual_gemm_kernel<<<654, 512, 0, stream>>>(lnx, w1b, asp_b1, asp_lng, asp_w2, hpart,
                                            ctxA, winb, b_in, qkvb);
  // 3) attention (2048) + ATE head finish from partials (128)
  finattn_kernel<<<2176, 256, 0, stream>>>(hpart, asp_lng, asp_lnb, asp_w2, asp_b2, out,
                                           qkvb, st, en, ctxO);
  // 4) proj GEMM (BM=64: 60 mb x 6 nb = 360 blocks)
  gemm_swz64<64, 128, 32, 64, 0><<<360, 256, 0, stream>>>(
      ctxO, woutb, b_out, projO, 3840, 768, 768, 6);
  // 5) masked means
  means_kernel<<<256, 256, 0, stream>>>(seq, projO, st, en, comb);
  // 6) fusion GEMM (BM=BN=64: 4 mb x 12 nb = 48 blocks)
  gemm_swz64<64, 64, 32, 32, 1><<<48, 256, 0, stream>>>(
      comb, fusb, fus_b, fusO, 256, 768, 1536, 12);
  // 7) APC all-in-one
  apc_all_kernel<<<64, 256, 0, stream>>>(fusO, apc_g, apc_b, senb, sen_b1,
                                         sen_lng, sen_lnb, sen_w2, sen_b2, out + 65536);
}